// Round 12
// baseline (233.979 us; speedup 1.0000x reference)
//
#include <hip/hip_runtime.h>
#include <hip/hip_bf16.h>

#define NROWS 8192
#define NDIM  1024
#define ESCALE 8192.0f
#define EINV   (1.0f / 8192.0f)
#define SCALE1 0x7F7F7F7F   // e8m0 = 127 -> 2^0 in every byte

// packed tile constants (16B-inner layout: [kseg16][row(128)][16B])
#define XTILE_B  131072ull   // bytes per packed fp8 x tile: 128 rows * 1024 k
#define PTILE_B  1048576ull  // bytes per packed fp8 E/Vt tile: 128 rows * 8192 k

typedef __attribute__((ext_vector_type(8))) int intx8;
typedef __attribute__((ext_vector_type(4))) int intx4;
typedef __attribute__((ext_vector_type(4))) float floatx4;

// async global->LDS. HW writes to (wave-uniform lds_base) + lane*16.
__device__ __forceinline__ void async16(void* lds, const void* g) {
  __builtin_amdgcn_global_load_lds(
      (const __attribute__((address_space(1))) unsigned int*)g,
      (__attribute__((address_space(3))) unsigned int*)lds, 16, 0, 0);
}

__device__ __forceinline__ unsigned char f2f8(float f) {
  return (unsigned char)(__builtin_amdgcn_cvt_pk_fp8_f32(f, 0.f, 0, false) & 0xff);
}

// counted wait: previous buffer's 8 staging loads done, next tile's stay in
// flight across the barrier (T4).
#define WAIT8_BAR()                                      \
  asm volatile("s_waitcnt vmcnt(8)" ::: "memory");       \
  __builtin_amdgcn_s_barrier();                          \
  __builtin_amdgcn_sched_barrier(0)
#define WAIT0_BAR()                                      \
  asm volatile("s_waitcnt vmcnt(0)" ::: "memory");       \
  __builtin_amdgcn_s_barrier();                          \
  __builtin_amdgcn_sched_barrier(0)

// read a 32-byte A/B fragment (k = quad*32..+31) from a 16B-inner LDS tile
__device__ __forceinline__ intx8 frag32s(const unsigned char* base, int quad, int row,
                                         int segsz) {
  const intx4 lo = *reinterpret_cast<const intx4*>(base + (2 * quad) * segsz + row * 16);
  const intx4 hi = *reinterpret_cast<const intx4*>(base + (2 * quad + 1) * segsz + row * 16);
  return __builtin_shufflevector(lo, hi, 0, 1, 2, 3, 4, 5, 6, 7);
}

// ------- Kernel P: fused pre-pass --------------------------------------
// Replaces k_norm + k_tr8 + lsum memset (3 graph nodes -> 1; emb HBM read
// 64 MB -> 32 MB + 32 MB LLC re-read).
// Block = 32 rows x 1024 cols. Phase 1: stream 16 chunks of 32x64 through an
// LDS transpose tile -> write Vt8 (raw emb, transposed, fp8) + accumulate
// per-row sumsq partials (8 threads/row). Phase 2: 8-lane shuffle-combine ->
// rinv. Phase 3: re-read chunk (LLC-warm) -> write xb = fp8(16*x/||x||).
__global__ __launch_bounds__(256) void k_prep(const float* __restrict__ emb,
                                              unsigned char* __restrict__ xb,
                                              unsigned char* __restrict__ Vt8,
                                              float* __restrict__ lsum) {
  __shared__ float T[64][33];   // [col-local][row-local], pitch 33
  __shared__ float rinv_s[32];
  const int t = threadIdx.x;
  const int r0 = blockIdx.x * 32;

  if (t < 32) lsum[r0 + t] = 0.f;   // replaces hipMemsetAsync

  float ss = 0.f;                   // sumsq partial: row t>>3, col-oct t&7
  const int pr = t >> 3, po = t & 7;

  for (int ci = 0; ci < 16; ++ci) {
    const int c0 = ci * 64;
    // load 32 rows x 64 cols into T (transposed): 2 float4 per thread
#pragma unroll
    for (int p = 0; p < 2; ++p) {
      const int r = (t >> 4) + 16 * p;
      const int c = (t & 15) * 4;
      const float4 v =
          *reinterpret_cast<const float4*>(emb + (size_t)(r0 + r) * NDIM + c0 + c);
      T[c + 0][r] = v.x; T[c + 1][r] = v.y; T[c + 2][r] = v.z; T[c + 3][r] = v.w;
    }
    __syncthreads();
    // sumsq partial: 8 threads per row, 8 cols each
#pragma unroll
    for (int i = 0; i < 8; ++i) {
      const float x = T[po * 8 + i][pr];
      ss += x * x;
    }
    // transposed write: d = t>>2 (64 cols), seg = t&3 (4 j-octs of 8)
    {
      const int d = t >> 2, seg = t & 3;
      const float* src = &T[d][seg * 8];
      int w0 = __builtin_amdgcn_cvt_pk_fp8_f32(src[0], src[1], 0, false);
      w0 = __builtin_amdgcn_cvt_pk_fp8_f32(src[2], src[3], w0, true);
      int w1 = __builtin_amdgcn_cvt_pk_fp8_f32(src[4], src[5], 0, false);
      w1 = __builtin_amdgcn_cvt_pk_fp8_f32(src[6], src[7], w1, true);
      const int dg = c0 + d;          // global d
      const int jg = r0 + seg * 8;    // global j
      unsigned char* dst = Vt8 + (size_t)(dg >> 7) * PTILE_B +
                           (jg >> 4) * 2048 + (dg & 127) * 16 + (jg & 15);
      int2 o; o.x = w0; o.y = w1;
      *reinterpret_cast<int2*>(dst) = o;
    }
    __syncthreads();   // T reused next chunk
  }

  // Phase 2: combine 8 partials per row (lanes pr*8+po are wave-contiguous)
  ss += __shfl_xor(ss, 1);
  ss += __shfl_xor(ss, 2);
  ss += __shfl_xor(ss, 4);
  if (po == 0) rinv_s[pr] = 1.0f / fmaxf(sqrtf(ss), 1e-12f);
  __syncthreads();

  // Phase 3: re-read chunk (LLC-warm), write packed xb
#pragma unroll 1
  for (int ci = 0; ci < 32; ++ci) {
    const int r = t >> 3;                       // 0..31
    const int c = ci * 32 + (t & 7) * 4;        // 0..1023
    const float4 v =
        *reinterpret_cast<const float4*>(emb + (size_t)(r0 + r) * NDIM + c);
    const float r16 = 16.0f * rinv_s[r];
    int pk = __builtin_amdgcn_cvt_pk_fp8_f32(v.x * r16, v.y * r16, 0, false);
    pk = __builtin_amdgcn_cvt_pk_fp8_f32(v.z * r16, v.w * r16, pk, true);
    const int row = r0 + r;
    unsigned char* dst = xb + (size_t)(row >> 7) * XTILE_B +
                         (c >> 4) * 2048 + (row & 127) * 16 + (c & 15);
    *reinterpret_cast<int*>(dst) = pk;
  }
}

// ---- Kernel 3a: symmetric S -> E fp8 (packed), triangle grid, MX K=128 ----
// (256,2) low-register class (r9: 2 blocks/CU, +40%) + counted-vmcnt (r11).
__global__ __launch_bounds__(256, 2) void k_s_sym(const unsigned char* __restrict__ xb,
                                                  unsigned char* __restrict__ E,
                                                  float* __restrict__ lsum) {
  __shared__ __align__(16) unsigned char smem[65536];  // [buf0: A|B][buf1: A|B]
  const int tid = threadIdx.x;
  const int lane = tid & 63, w = tid >> 6;
  const int quad = lane >> 4, l15 = lane & 15;
  const int wi = w >> 1, wj = w & 1;

  // XCD-contiguous bijective remap: 2080 blocks = 8 XCD * 260
  const int idx = (blockIdx.x & 7) * 260 + (blockIdx.x >> 3);
  int bj = (int)((sqrtf(8.0f * idx + 1.0f) - 1.0f) * 0.5f);
  while ((bj + 1) * (bj + 2) / 2 <= idx) ++bj;
  while (bj * (bj + 1) / 2 > idx) --bj;
  const int bi = idx - bj * (bj + 1) / 2;
  const int it0 = bi * 128, jt0 = bj * 128;

  floatx4 acc[4][4];
#pragma unroll
  for (int a = 0; a < 4; ++a)
#pragma unroll
    for (int b = 0; b < 4; ++b) acc[a][b] = {0.f, 0.f, 0.f, 0.f};

  const unsigned char* gA = xb + (size_t)bi * XTILE_B + w * 4096 + lane * 16;
  const unsigned char* gB = xb + (size_t)bj * XTILE_B + w * 4096 + lane * 16;

  auto STAGE = [&](int buf) {  // 8 async16 per wave
    unsigned char* lA = smem + buf * 32768 + w * 4096;
    unsigned char* lB = lA + 16384;
#pragma unroll
    for (int q = 0; q < 4; ++q) {
      async16(lA + q * 1024, gA + q * 1024);
      async16(lB + q * 1024, gB + q * 1024);
    }
    gA += 16384; gB += 16384;
  };
  auto COMPUTE = [&](int buf) {
    const unsigned char* Ab = smem + buf * 32768;
    const unsigned char* Bb = Ab + 16384;
    intx8 af[4];
#pragma unroll
    for (int fm = 0; fm < 4; ++fm)
      af[fm] = frag32s(Ab, quad, wi * 64 + fm * 16 + l15, 2048);
    __builtin_amdgcn_s_setprio(1);
#pragma unroll
    for (int fn = 0; fn < 4; ++fn) {
      const intx8 bf = frag32s(Bb, quad, wj * 64 + fn * 16 + l15, 2048);
#pragma unroll
      for (int fm = 0; fm < 4; ++fm)
        acc[fm][fn] = __builtin_amdgcn_mfma_scale_f32_16x16x128_f8f6f4(
            af[fm], bf, acc[fm][fn], 0, 0, 0, SCALE1, 0, SCALE1);
    }
    __builtin_amdgcn_s_setprio(0);
  };

  // 8 K-tiles, 2-phase dbuf, counted-vmcnt sync (no vmcnt(0) drain in loop)
  STAGE(0);
#pragma unroll 1
  for (int kk = 0; kk < 3; ++kk) {
    STAGE(1); WAIT8_BAR(); COMPUTE(0); __builtin_amdgcn_s_barrier();
    STAGE(0); WAIT8_BAR(); COMPUTE(1); __builtin_amdgcn_s_barrier();
  }
  STAGE(1); WAIT8_BAR(); COMPUTE(0);
  WAIT0_BAR(); COMPUTE(1);

  // P = exp(10*s - 10); s_raw = 256*s (x scaled by 16 each side)
#pragma unroll
  for (int fm = 0; fm < 4; ++fm)
#pragma unroll
    for (int fn = 0; fn < 4; ++fn)
#pragma unroll
      for (int reg = 0; reg < 4; ++reg) {
        float p = __expf(fmaf(acc[fm][fn][reg], 10.0f / 256.0f, -10.f));
        if (bi == bj &&
            (wi * 64 + fm * 16 + quad * 4 + reg) == (wj * 64 + fn * 16 + l15))
          p = 0.f;
        acc[fm][fn][reg] = p;
      }

  // normal-orientation packed stores + row sums
  unsigned char* Ei = E + (size_t)bi * PTILE_B;
#pragma unroll
  for (int fm = 0; fm < 4; ++fm)
#pragma unroll
    for (int reg = 0; reg < 4; ++reg) {
      const int row = wi * 64 + fm * 16 + quad * 4 + reg;
      float s = 0.f;
#pragma unroll
      for (int fn = 0; fn < 4; ++fn) {
        const float p = acc[fm][fn][reg];
        s += p;
        Ei[((jt0 >> 4) + wj * 4 + fn) * 2048 + row * 16 + l15] = f2f8(p * ESCALE);
      }
#pragma unroll
      for (int m = 1; m < 16; m <<= 1) s += __shfl_xor(s, m);
      if (l15 == 0) unsafeAtomicAdd(&lsum[it0 + row], s);
    }

  if (bi != bj) {  // transposed packed store + col sums
    unsigned char* Ej = E + (size_t)bj * PTILE_B;
#pragma unroll
    for (int fn = 0; fn < 4; ++fn) {
      const int col = wj * 64 + fn * 16 + l15;  // i-local row within tile bj
      float cs = 0.f;
#pragma unroll
      for (int fm = 0; fm < 4; ++fm) {
        int pk = __builtin_amdgcn_cvt_pk_fp8_f32(acc[fm][fn][0] * ESCALE,
                                                 acc[fm][fn][1] * ESCALE, 0, false);
        pk = __builtin_amdgcn_cvt_pk_fp8_f32(acc[fm][fn][2] * ESCALE,
                                             acc[fm][fn][3] * ESCALE, pk, true);
        cs += acc[fm][fn][0] + acc[fm][fn][1] + acc[fm][fn][2] + acc[fm][fn][3];
        *reinterpret_cast<int*>(
            &Ej[((it0 >> 4) + wi * 4 + fm) * 2048 + col * 16 + quad * 4]) = pk;
      }
      cs += __shfl_xor(cs, 16);
      cs += __shfl_xor(cs, 32);
      if (quad == 0) unsafeAtomicAdd(&lsum[jt0 + col], cs);
    }
  }
}

// ---------------- Kernel 3b: full-grid fallback (chunked, packed) ----------
__global__ __launch_bounds__(256) void k_s_full(const unsigned char* __restrict__ xb,
                                                unsigned char* __restrict__ E,
                                                float* __restrict__ lsum, int ch0) {
  __shared__ __align__(16) unsigned char smem[65536];
  const int tid = threadIdx.x;
  const int lane = tid & 63, w = tid >> 6;
  const int quad = lane >> 4, l15 = lane & 15;
  const int wi = w >> 1, wj = w & 1;
  const int bi = blockIdx.x;       // chunk-local i tile
  const int bj = blockIdx.y;       // global j tile
  const int it0 = bi * 128, jt0 = bj * 128;

  floatx4 acc[4][4];
#pragma unroll
  for (int a = 0; a < 4; ++a)
#pragma unroll
    for (int b = 0; b < 4; ++b) acc[a][b] = {0.f, 0.f, 0.f, 0.f};

  const unsigned char* gA =
      xb + (size_t)((ch0 >> 7) + bi) * XTILE_B + w * 4096 + lane * 16;
  const unsigned char* gB = xb + (size_t)bj * XTILE_B + w * 4096 + lane * 16;

  auto STAGE = [&](int buf) {
    unsigned char* lA = smem + buf * 32768 + w * 4096;
    unsigned char* lB = lA + 16384;
#pragma unroll
    for (int q = 0; q < 4; ++q) {
      async16(lA + q * 1024, gA + q * 1024);
      async16(lB + q * 1024, gB + q * 1024);
    }
    gA += 16384; gB += 16384;
  };
  auto COMPUTE = [&](int buf) {
    const unsigned char* Ab = smem + buf * 32768;
    const unsigned char* Bb = Ab + 16384;
    intx8 bf[4];
#pragma unroll
    for (int fn = 0; fn < 4; ++fn)
      bf[fn] = frag32s(Bb, quad, wj * 64 + fn * 16 + l15, 2048);
    __builtin_amdgcn_s_setprio(1);
#pragma unroll
    for (int fm = 0; fm < 4; ++fm) {
      const intx8 af = frag32s(Ab, quad, wi * 64 + fm * 16 + l15, 2048);
#pragma unroll
      for (int fn = 0; fn < 4; ++fn)
        acc[fm][fn] = __builtin_amdgcn_mfma_scale_f32_16x16x128_f8f6f4(
            af, bf[fn], acc[fm][fn], 0, 0, 0, SCALE1, 0, SCALE1);
    }
    __builtin_amdgcn_s_setprio(0);
  };

  STAGE(0);
  __syncthreads();
#pragma unroll
  for (int kk = 0; kk < 6; kk += 2) {
    STAGE(1); COMPUTE(0); __syncthreads();
    STAGE(0); COMPUTE(1); __syncthreads();
  }
  STAGE(1); COMPUTE(0); __syncthreads(); COMPUTE(1);

  unsigned char* Ei = E + (size_t)bi * PTILE_B;
#pragma unroll
  for (int fm = 0; fm < 4; ++fm)
#pragma unroll
    for (int reg = 0; reg < 4; ++reg) {
      const int row = wi * 64 + fm * 16 + quad * 4 + reg;
      float s = 0.f;
#pragma unroll
      for (int fn = 0; fn < 4; ++fn) {
        const int col = jt0 + wj * 64 + fn * 16 + l15;
        float p = __expf(fmaf(acc[fm][fn][reg], 10.0f / 256.0f, -10.f));
        if (ch0 + it0 + row == col) p = 0.f;
        s += p;
        Ei[(col >> 4) * 2048 + row * 16 + (col & 15)] = f2f8(p * ESCALE);
      }
#pragma unroll
      for (int m = 1; m < 16; m <<= 1) s += __shfl_xor(s, m);
      if (l15 == 0) unsafeAtomicAdd(&lsum[ch0 + it0 + row], s);
    }
}

// -------- Kernel 4: out^T = Vt8 @ E^T (MX fp8 K=128, packed operands) ------
// (256,2) fn-halves body (r9) + counted-vmcnt sync (r11).
__global__ __launch_bounds__(256, 2) void k_pv8(const unsigned char* __restrict__ E,
                                                const unsigned char* __restrict__ Vt8,
                                                const float* __restrict__ lsum,
                                                const float* __restrict__ emb,
                                                float* __restrict__ out,
                                                int swz, int ch0) {
  __shared__ __align__(16) unsigned char smem[65536];
  const int tid = threadIdx.x;
  const int lane = tid & 63, w = tid >> 6;
  const int quad = lane >> 4, l15 = lane & 15;
  const int wi = w >> 1, wj = w & 1;

  int dt, it;
  if (swz) {
    const int n = blockIdx.x;
    const int r = n & 7, q = n >> 3;
    dt = q >> 3; it = (q & 7) * 8 + r;
  } else {
    dt = blockIdx.x; it = blockIdx.y;
  }
  const int dt0 = dt * 128, it0 = it * 128;

  floatx4 acc[4][4];
#pragma unroll
  for (int a = 0; a < 4; ++a)
#pragma unroll
    for (int b = 0; b < 4; ++b) acc[a][b] = {0.f, 0.f, 0.f, 0.f};

  const unsigned char* gA = Vt8 + (size_t)dt * PTILE_B + w * 4096 + lane * 16;
  const unsigned char* gB = E + (size_t)it * PTILE_B + w * 4096 + lane * 16;

  auto STAGE = [&](int buf) {  // 8 async16 per wave
    unsigned char* lA = smem + buf * 32768 + w * 4096;
    unsigned char* lB = lA + 16384;
#pragma unroll
    for (int q = 0; q < 4; ++q) {
      async16(lA + q * 1024, gA + q * 1024);
      async16(lB + q * 1024, gB + q * 1024);
    }
    gA += 16384; gB += 16384;
  };
  auto COMPUTE = [&](int buf) {
    const unsigned char* Ab = smem + buf * 32768;
    const unsigned char* Bb = Ab + 16384;
    __builtin_amdgcn_s_setprio(1);
#pragma unroll
    for (int h = 0; h < 2; ++h) {
      const intx8 bf0 = frag32s(Bb, quad, wj * 64 + (2 * h) * 16 + l15, 2048);
      const intx8 bf1 = frag32s(Bb, quad, wj * 64 + (2 * h + 1) * 16 + l15, 2048);
#pragma unroll
      for (int fm = 0; fm < 4; ++fm) {
        const intx8 af = frag32s(Ab, quad, wi * 64 + fm * 16 + l15, 2048);
        acc[fm][2 * h] = __builtin_amdgcn_mfma_scale_f32_16x16x128_f8f6f4(
            af, bf0, acc[fm][2 * h], 0, 0, 0, SCALE1, 0, SCALE1);
        acc[fm][2 * h + 1] = __builtin_amdgcn_mfma_scale_f32_16x16x128_f8f6f4(
            af, bf1, acc[fm][2 * h + 1], 0, 0, 0, SCALE1, 0, SCALE1);
      }
    }
    __builtin_amdgcn_s_setprio(0);
  };

  // 64 K-tiles, 2-phase dbuf, counted-vmcnt sync
  STAGE(0);
#pragma unroll 1
  for (int kk = 0; kk < 31; ++kk) {
    STAGE(1); WAIT8_BAR(); COMPUTE(0); __builtin_amdgcn_s_barrier();
    STAGE(0); WAIT8_BAR(); COMPUTE(1); __builtin_amdgcn_s_barrier();
  }
  STAGE(1); WAIT8_BAR(); COMPUTE(0);
  WAIT0_BAR(); COMPUTE(1);

#pragma unroll
  for (int fn = 0; fn < 4; ++fn) {
    const int i = it0 + wj * 64 + fn * 16 + l15;
    const float rinv = 1.0f / (1.0f + lsum[ch0 + i]);
#pragma unroll
    for (int fm = 0; fm < 4; ++fm) {
      const int d = dt0 + wi * 64 + fm * 16 + quad * 4;
      const float4 e = *reinterpret_cast<const float4*>(emb + (size_t)(ch0 + i) * NDIM + d);
      float4 o;
      o.x = (e.x + acc[fm][fn][0] * EINV) * rinv;
      o.y = (e.y + acc[fm][fn][1] * EINV) * rinv;
      o.z = (e.z + acc[fm][fn][2] * EINV) * rinv;
      o.w = (e.w + acc[fm][fn][3] * EINV) * rinv;
      *reinterpret_cast<float4*>(out + (size_t)(ch0 + i) * NDIM + d) = o;
    }
  }
}

extern "C" void kernel_launch(void* const* d_in, const int* in_sizes, int n_in,
                              void* d_out, int out_size, void* d_ws, size_t ws_size,
                              hipStream_t stream) {
  const float* emb = (const float*)d_in[0];
  float* out = (float*)d_out;

  unsigned char* xb = (unsigned char*)d_ws;                            // 8 MB packed fp8
  unsigned char* Vt8 = (unsigned char*)((char*)d_ws + (8ull << 20));   // 8 MB packed fp8
  float* lsum = (float*)((char*)d_ws + (16ull << 20));                 // 32 KB
  unsigned char* E = (unsigned char*)((char*)d_ws + (17ull << 20));    // 64 MB packed fp8

  const size_t avail = ws_size > (17ull << 20) ? ws_size - (17ull << 20) : 0;
  int nc = 1;
  while (nc < 64 && ((size_t)(NROWS / nc) * NROWS) > avail) nc <<= 1;
  const int RC = NROWS / nc;

  // fused pre-pass: zeroes lsum, writes xb + Vt8 (replaces memset+k_norm+k_tr8)
  k_prep<<<NROWS / 32, 256, 0, stream>>>(emb, xb, Vt8, lsum);

  if (nc == 1) {
    const int nt = NROWS / 128;
    k_s_sym<<<nt * (nt + 1) / 2, 256, 0, stream>>>(xb, E, lsum);
    k_pv8<<<512, 256, 0, stream>>>(E, Vt8, lsum, emb, out, 1, 0);
  } else {
    for (int c = 0; c < nc; ++c) {
      const int ch0 = c * RC;
      k_s_full<<<dim3(RC / 128, NROWS / 128), 256, 0, stream>>>(xb, E, lsum, ch0);
      k_pv8<<<dim3(NDIM / 128, RC / 128), 256, 0, stream>>>(E, Vt8, lsum, emb, out, 0, ch0);
    }
  }
}

// Round 13
// 229.237 us; speedup vs baseline: 1.0207x; 1.0207x over previous
//
#include <hip/hip_runtime.h>
#include <hip/hip_bf16.h>

#define NROWS 8192
#define NDIM  1024
#define ESCALE 8192.0f
#define EINV   (1.0f / 8192.0f)
#define SCALE1 0x7F7F7F7F   // e8m0 = 127 -> 2^0 in every byte

// packed tile constants (16B-inner layout: [kseg16][row(128)][16B])
#define XTILE_B  131072ull   // bytes per packed fp8 x tile: 128 rows * 1024 k
#define PTILE_B  1048576ull  // bytes per packed fp8 E/Vt tile: 128 rows * 8192 k

typedef __attribute__((ext_vector_type(8))) int intx8;
typedef __attribute__((ext_vector_type(4))) int intx4;
typedef __attribute__((ext_vector_type(4))) float floatx4;

// async global->LDS. HW writes to (wave-uniform lds_base) + lane*16.
__device__ __forceinline__ void async16(void* lds, const void* g) {
  __builtin_amdgcn_global_load_lds(
      (const __attribute__((address_space(1))) unsigned int*)g,
      (__attribute__((address_space(3))) unsigned int*)lds, 16, 0, 0);
}

__device__ __forceinline__ unsigned char f2f8(float f) {
  return (unsigned char)(__builtin_amdgcn_cvt_pk_fp8_f32(f, 0.f, 0, false) & 0xff);
}

// read a 32-byte A/B fragment (k = quad*32..+31) from a 16B-inner LDS tile
__device__ __forceinline__ intx8 frag32s(const unsigned char* base, int quad, int row,
                                         int segsz) {
  const intx4 lo = *reinterpret_cast<const intx4*>(base + (2 * quad) * segsz + row * 16);
  const intx4 hi = *reinterpret_cast<const intx4*>(base + (2 * quad + 1) * segsz + row * 16);
  return __builtin_shufflevector(lo, hi, 0, 1, 2, 3, 4, 5, 6, 7);
}

// ------- Kernel 1: row L2-normalize -> fp8(16*x), TILE-PACKED ----------
__global__ __launch_bounds__(256) void k_norm(const float* __restrict__ emb,
                                              unsigned char* __restrict__ xb) {
  __shared__ float red[4];
  __shared__ float s_rinv;
  const int row = blockIdx.x;
  const int t = threadIdx.x;
  const float4 v = reinterpret_cast<const float4*>(emb + (size_t)row * NDIM)[t];
  float ss = v.x * v.x + v.y * v.y + v.z * v.z + v.w * v.w;
#pragma unroll
  for (int off = 32; off > 0; off >>= 1) ss += __shfl_down(ss, off);
  if ((t & 63) == 0) red[t >> 6] = ss;
  __syncthreads();
  if (t == 0) s_rinv = 1.0f / fmaxf(sqrtf(red[0] + red[1] + red[2] + red[3]), 1e-12f);
  __syncthreads();
  const float r16 = 16.0f * s_rinv;
  int pk = __builtin_amdgcn_cvt_pk_fp8_f32(v.x * r16, v.y * r16, 0, false);
  pk = __builtin_amdgcn_cvt_pk_fp8_f32(v.z * r16, v.w * r16, pk, true);
  const int k = t * 4;
  unsigned char* dst = xb + (size_t)(row >> 7) * XTILE_B +
                       (k >> 4) * 2048 + (row & 127) * 16 + (k & 15);
  *reinterpret_cast<int*>(dst) = pk;
}

// ------- Kernel 2: transpose emb -> Vt fp8, TILE-PACKED ----------
// Pitch 73 (was 72): 72 gave c*72 === c*8 (mod 32) with c===0 mod 4 -> all 16
// lanes in one bank (16-way conflict) on BOTH phases. 73 -> ~2-way (free).
__global__ __launch_bounds__(256) void k_tr8(const float* __restrict__ emb,
                                             unsigned char* __restrict__ Vt8) {
  __shared__ float T[64][73];
  const int r0 = blockIdx.x * 64;  // source rows (j of Vt)
  const int c0 = blockIdx.y * 64;  // source cols (d of Vt)
  const int t = threadIdx.x;
#pragma unroll
  for (int p = 0; p < 4; ++p) {
    const int r = (t >> 4) + 16 * p;
    const int c = (t & 15) * 4;
    const float4 v = *reinterpret_cast<const float4*>(emb + (size_t)(r0 + r) * NDIM + c0 + c);
    T[c + 0][r] = v.x; T[c + 1][r] = v.y; T[c + 2][r] = v.z; T[c + 3][r] = v.w;
  }
  __syncthreads();
#pragma unroll
  for (int p = 0; p < 2; ++p) {
    const int d = (t >> 3) + 32 * p;
    const int seg = t & 7;
    const float* src = &T[d][seg * 8];
    int w0 = __builtin_amdgcn_cvt_pk_fp8_f32(src[0], src[1], 0, false);
    w0 = __builtin_amdgcn_cvt_pk_fp8_f32(src[2], src[3], w0, true);
    int w1 = __builtin_amdgcn_cvt_pk_fp8_f32(src[4], src[5], 0, false);
    w1 = __builtin_amdgcn_cvt_pk_fp8_f32(src[6], src[7], w1, true);
    const int dg = c0 + d;          // global d
    const int jg = r0 + seg * 8;    // global j
    unsigned char* dst = Vt8 + (size_t)(dg >> 7) * PTILE_B +
                         (jg >> 4) * 2048 + (dg & 127) * 16 + (jg & 15);
    int2 o; o.x = w0; o.y = w1;
    *reinterpret_cast<int2*>(dst) = o;
  }
}

// ---- Kernel 3a: symmetric S -> E fp8 (packed), triangle grid, MX K=128 ----
// (256,2) low-register class (r9: 2 blocks/CU, +40%). af[4]-held COMPUTE,
// plain __syncthreads 2-phase (r10 verified best: other block covers drain).
__global__ __launch_bounds__(256, 2) void k_s_sym(const unsigned char* __restrict__ xb,
                                                  unsigned char* __restrict__ E,
                                                  float* __restrict__ lsum) {
  __shared__ __align__(16) unsigned char smem[65536];  // [buf0: A|B][buf1: A|B]
  const int tid = threadIdx.x;
  const int lane = tid & 63, w = tid >> 6;
  const int quad = lane >> 4, l15 = lane & 15;
  const int wi = w >> 1, wj = w & 1;

  // XCD-contiguous bijective remap: 2080 blocks = 8 XCD * 260
  const int idx = (blockIdx.x & 7) * 260 + (blockIdx.x >> 3);
  int bj = (int)((sqrtf(8.0f * idx + 1.0f) - 1.0f) * 0.5f);
  while ((bj + 1) * (bj + 2) / 2 <= idx) ++bj;
  while (bj * (bj + 1) / 2 > idx) --bj;
  const int bi = idx - bj * (bj + 1) / 2;
  const int it0 = bi * 128, jt0 = bj * 128;

  floatx4 acc[4][4];
#pragma unroll
  for (int a = 0; a < 4; ++a)
#pragma unroll
    for (int b = 0; b < 4; ++b) acc[a][b] = {0.f, 0.f, 0.f, 0.f};

  const unsigned char* gA = xb + (size_t)bi * XTILE_B + w * 4096 + lane * 16;
  const unsigned char* gB = xb + (size_t)bj * XTILE_B + w * 4096 + lane * 16;

  auto STAGE = [&](int buf) {  // 8 async16 per wave
    unsigned char* lA = smem + buf * 32768 + w * 4096;
    unsigned char* lB = lA + 16384;
#pragma unroll
    for (int q = 0; q < 4; ++q) {
      async16(lA + q * 1024, gA + q * 1024);
      async16(lB + q * 1024, gB + q * 1024);
    }
    gA += 16384; gB += 16384;
  };
  auto COMPUTE = [&](int buf) {
    const unsigned char* Ab = smem + buf * 32768;
    const unsigned char* Bb = Ab + 16384;
    intx8 af[4];
#pragma unroll
    for (int fm = 0; fm < 4; ++fm)
      af[fm] = frag32s(Ab, quad, wi * 64 + fm * 16 + l15, 2048);
    __builtin_amdgcn_s_setprio(1);
#pragma unroll
    for (int fn = 0; fn < 4; ++fn) {
      const intx8 bf = frag32s(Bb, quad, wj * 64 + fn * 16 + l15, 2048);
#pragma unroll
      for (int fm = 0; fm < 4; ++fm)
        acc[fm][fn] = __builtin_amdgcn_mfma_scale_f32_16x16x128_f8f6f4(
            af[fm], bf, acc[fm][fn], 0, 0, 0, SCALE1, 0, SCALE1);
    }
    __builtin_amdgcn_s_setprio(0);
  };

  // 8 K-tiles, 2-phase dbuf (unroll 1 keeps register pressure down)
  STAGE(0);
  __syncthreads();
#pragma unroll 1
  for (int kk = 0; kk < 3; ++kk) {
    STAGE(1); COMPUTE(0); __syncthreads();
    STAGE(0); COMPUTE(1); __syncthreads();
  }
  STAGE(1); COMPUTE(0); __syncthreads(); COMPUTE(1);

  // P = exp(10*s - 10); s_raw = 256*s (x scaled by 16 each side)
#pragma unroll
  for (int fm = 0; fm < 4; ++fm)
#pragma unroll
    for (int fn = 0; fn < 4; ++fn)
#pragma unroll
      for (int reg = 0; reg < 4; ++reg) {
        float p = __expf(fmaf(acc[fm][fn][reg], 10.0f / 256.0f, -10.f));
        if (bi == bj &&
            (wi * 64 + fm * 16 + quad * 4 + reg) == (wj * 64 + fn * 16 + l15))
          p = 0.f;
        acc[fm][fn][reg] = p;
      }

  // normal-orientation packed stores + row sums
  unsigned char* Ei = E + (size_t)bi * PTILE_B;
#pragma unroll
  for (int fm = 0; fm < 4; ++fm)
#pragma unroll
    for (int reg = 0; reg < 4; ++reg) {
      const int row = wi * 64 + fm * 16 + quad * 4 + reg;
      float s = 0.f;
#pragma unroll
      for (int fn = 0; fn < 4; ++fn) {
        const float p = acc[fm][fn][reg];
        s += p;
        Ei[((jt0 >> 4) + wj * 4 + fn) * 2048 + row * 16 + l15] = f2f8(p * ESCALE);
      }
#pragma unroll
      for (int m = 1; m < 16; m <<= 1) s += __shfl_xor(s, m);
      if (l15 == 0) unsafeAtomicAdd(&lsum[it0 + row], s);
    }

  if (bi != bj) {  // transposed packed store + col sums
    unsigned char* Ej = E + (size_t)bj * PTILE_B;
#pragma unroll
    for (int fn = 0; fn < 4; ++fn) {
      const int col = wj * 64 + fn * 16 + l15;  // i-local row within tile bj
      float cs = 0.f;
#pragma unroll
      for (int fm = 0; fm < 4; ++fm) {
        int pk = __builtin_amdgcn_cvt_pk_fp8_f32(acc[fm][fn][0] * ESCALE,
                                                 acc[fm][fn][1] * ESCALE, 0, false);
        pk = __builtin_amdgcn_cvt_pk_fp8_f32(acc[fm][fn][2] * ESCALE,
                                             acc[fm][fn][3] * ESCALE, pk, true);
        cs += acc[fm][fn][0] + acc[fm][fn][1] + acc[fm][fn][2] + acc[fm][fn][3];
        *reinterpret_cast<int*>(
            &Ej[((it0 >> 4) + wi * 4 + fm) * 2048 + col * 16 + quad * 4]) = pk;
      }
      cs += __shfl_xor(cs, 16);
      cs += __shfl_xor(cs, 32);
      if (quad == 0) unsafeAtomicAdd(&lsum[jt0 + col], cs);
    }
  }
}

// ---------------- Kernel 3b: full-grid fallback (chunked, packed) ----------
__global__ __launch_bounds__(256) void k_s_full(const unsigned char* __restrict__ xb,
                                                unsigned char* __restrict__ E,
                                                float* __restrict__ lsum, int ch0) {
  __shared__ __align__(16) unsigned char smem[65536];
  const int tid = threadIdx.x;
  const int lane = tid & 63, w = tid >> 6;
  const int quad = lane >> 4, l15 = lane & 15;
  const int wi = w >> 1, wj = w & 1;
  const int bi = blockIdx.x;       // chunk-local i tile
  const int bj = blockIdx.y;       // global j tile
  const int it0 = bi * 128, jt0 = bj * 128;

  floatx4 acc[4][4];
#pragma unroll
  for (int a = 0; a < 4; ++a)
#pragma unroll
    for (int b = 0; b < 4; ++b) acc[a][b] = {0.f, 0.f, 0.f, 0.f};

  const unsigned char* gA =
      xb + (size_t)((ch0 >> 7) + bi) * XTILE_B + w * 4096 + lane * 16;
  const unsigned char* gB = xb + (size_t)bj * XTILE_B + w * 4096 + lane * 16;

  auto STAGE = [&](int buf) {
    unsigned char* lA = smem + buf * 32768 + w * 4096;
    unsigned char* lB = lA + 16384;
#pragma unroll
    for (int q = 0; q < 4; ++q) {
      async16(lA + q * 1024, gA + q * 1024);
      async16(lB + q * 1024, gB + q * 1024);
    }
    gA += 16384; gB += 16384;
  };
  auto COMPUTE = [&](int buf) {
    const unsigned char* Ab = smem + buf * 32768;
    const unsigned char* Bb = Ab + 16384;
    intx8 bf[4];
#pragma unroll
    for (int fn = 0; fn < 4; ++fn)
      bf[fn] = frag32s(Bb, quad, wj * 64 + fn * 16 + l15, 2048);
    __builtin_amdgcn_s_setprio(1);
#pragma unroll
    for (int fm = 0; fm < 4; ++fm) {
      const intx8 af = frag32s(Ab, quad, wi * 64 + fm * 16 + l15, 2048);
#pragma unroll
      for (int fn = 0; fn < 4; ++fn)
        acc[fm][fn] = __builtin_amdgcn_mfma_scale_f32_16x16x128_f8f6f4(
            af, bf[fn], acc[fm][fn], 0, 0, 0, SCALE1, 0, SCALE1);
    }
    __builtin_amdgcn_s_setprio(0);
  };

  STAGE(0);
  __syncthreads();
#pragma unroll
  for (int kk = 0; kk < 6; kk += 2) {
    STAGE(1); COMPUTE(0); __syncthreads();
    STAGE(0); COMPUTE(1); __syncthreads();
  }
  STAGE(1); COMPUTE(0); __syncthreads(); COMPUTE(1);

  unsigned char* Ei = E + (size_t)bi * PTILE_B;
#pragma unroll
  for (int fm = 0; fm < 4; ++fm)
#pragma unroll
    for (int reg = 0; reg < 4; ++reg) {
      const int row = wi * 64 + fm * 16 + quad * 4 + reg;
      float s = 0.f;
#pragma unroll
      for (int fn = 0; fn < 4; ++fn) {
        const int col = jt0 + wj * 64 + fn * 16 + l15;
        float p = __expf(fmaf(acc[fm][fn][reg], 10.0f / 256.0f, -10.f));
        if (ch0 + it0 + row == col) p = 0.f;
        s += p;
        Ei[(col >> 4) * 2048 + row * 16 + (col & 15)] = f2f8(p * ESCALE);
      }
#pragma unroll
      for (int m = 1; m < 16; m <<= 1) s += __shfl_xor(s, m);
      if (l15 == 0) unsafeAtomicAdd(&lsum[ch0 + it0 + row], s);
    }
}

// -------- Kernel 4: out^T = Vt8 @ E^T (MX fp8 K=128, packed operands) ------
// (256,2), fn-halves, plain 2-phase syncthreads (r10 verified best).
__global__ __launch_bounds__(256, 2) void k_pv8(const unsigned char* __restrict__ E,
                                                const unsigned char* __restrict__ Vt8,
                                                const float* __restrict__ lsum,
                                                const float* __restrict__ emb,
                                                float* __restrict__ out,
                                                int swz, int ch0) {
  __shared__ __align__(16) unsigned char smem[65536];
  const int tid = threadIdx.x;
  const int lane = tid & 63, w = tid >> 6;
  const int quad = lane >> 4, l15 = lane & 15;
  const int wi = w >> 1, wj = w & 1;

  int dt, it;
  if (swz) {
    const int n = blockIdx.x;
    const int r = n & 7, q = n >> 3;
    dt = q >> 3; it = (q & 7) * 8 + r;
  } else {
    dt = blockIdx.x; it = blockIdx.y;
  }
  const int dt0 = dt * 128, it0 = it * 128;

  floatx4 acc[4][4];
#pragma unroll
  for (int a = 0; a < 4; ++a)
#pragma unroll
    for (int b = 0; b < 4; ++b) acc[a][b] = {0.f, 0.f, 0.f, 0.f};

  const unsigned char* gA = Vt8 + (size_t)dt * PTILE_B + w * 4096 + lane * 16;
  const unsigned char* gB = E + (size_t)it * PTILE_B + w * 4096 + lane * 16;

  auto STAGE = [&](int buf) {  // 8 async16 per wave
    unsigned char* lA = smem + buf * 32768 + w * 4096;
    unsigned char* lB = lA + 16384;
#pragma unroll
    for (int q = 0; q < 4; ++q) {
      async16(lA + q * 1024, gA + q * 1024);
      async16(lB + q * 1024, gB + q * 1024);
    }
    gA += 16384; gB += 16384;
  };
  auto COMPUTE = [&](int buf) {
    const unsigned char* Ab = smem + buf * 32768;
    const unsigned char* Bb = Ab + 16384;
    __builtin_amdgcn_s_setprio(1);
#pragma unroll
    for (int h = 0; h < 2; ++h) {
      const intx8 bf0 = frag32s(Bb, quad, wj * 64 + (2 * h) * 16 + l15, 2048);
      const intx8 bf1 = frag32s(Bb, quad, wj * 64 + (2 * h + 1) * 16 + l15, 2048);
#pragma unroll
      for (int fm = 0; fm < 4; ++fm) {
        const intx8 af = frag32s(Ab, quad, wi * 64 + fm * 16 + l15, 2048);
        acc[fm][2 * h] = __builtin_amdgcn_mfma_scale_f32_16x16x128_f8f6f4(
            af, bf0, acc[fm][2 * h], 0, 0, 0, SCALE1, 0, SCALE1);
        acc[fm][2 * h + 1] = __builtin_amdgcn_mfma_scale_f32_16x16x128_f8f6f4(
            af, bf1, acc[fm][2 * h + 1], 0, 0, 0, SCALE1, 0, SCALE1);
      }
    }
    __builtin_amdgcn_s_setprio(0);
  };

  // 64 K-tiles, 2-phase dbuf
  STAGE(0);
  __syncthreads();
#pragma unroll 1
  for (int kk = 0; kk < 31; ++kk) {
    STAGE(1); COMPUTE(0); __syncthreads();
    STAGE(0); COMPUTE(1); __syncthreads();
  }
  STAGE(1); COMPUTE(0); __syncthreads(); COMPUTE(1);

#pragma unroll
  for (int fn = 0; fn < 4; ++fn) {
    const int i = it0 + wj * 64 + fn * 16 + l15;
    const float rinv = 1.0f / (1.0f + lsum[ch0 + i]);
#pragma unroll
    for (int fm = 0; fm < 4; ++fm) {
      const int d = dt0 + wi * 64 + fm * 16 + quad * 4;
      const float4 e = *reinterpret_cast<const float4*>(emb + (size_t)(ch0 + i) * NDIM + d);
      float4 o;
      o.x = (e.x + acc[fm][fn][0] * EINV) * rinv;
      o.y = (e.y + acc[fm][fn][1] * EINV) * rinv;
      o.z = (e.z + acc[fm][fn][2] * EINV) * rinv;
      o.w = (e.w + acc[fm][fn][3] * EINV) * rinv;
      *reinterpret_cast<float4*>(out + (size_t)(ch0 + i) * NDIM + d) = o;
    }
  }
}

extern "C" void kernel_launch(void* const* d_in, const int* in_sizes, int n_in,
                              void* d_out, int out_size, void* d_ws, size_t ws_size,
                              hipStream_t stream) {
  const float* emb = (const float*)d_in[0];
  float* out = (float*)d_out;

  unsigned char* xb = (unsigned char*)d_ws;                            // 8 MB packed fp8
  unsigned char* Vt8 = (unsigned char*)((char*)d_ws + (8ull << 20));   // 8 MB packed fp8
  float* lsum = (float*)((char*)d_ws + (16ull << 20));                 // 32 KB
  unsigned char* E = (unsigned char*)((char*)d_ws + (17ull << 20));    // 64 MB packed fp8

  const size_t avail = ws_size > (17ull << 20) ? ws_size - (17ull << 20) : 0;
  int nc = 1;
  while (nc < 64 && ((size_t)(NROWS / nc) * NROWS) > avail) nc <<= 1;
  const int RC = NROWS / nc;

  hipMemsetAsync(lsum, 0, NROWS * sizeof(float), stream);
  k_norm<<<NROWS, 256, 0, stream>>>(emb, xb);
  k_tr8<<<dim3(NROWS / 64, NDIM / 64), 256, 0, stream>>>(emb, Vt8);

  if (nc == 1) {
    const int nt = NROWS / 128;
    k_s_sym<<<nt * (nt + 1) / 2, 256, 0, stream>>>(xb, E, lsum);
    k_pv8<<<512, 256, 0, stream>>>(E, Vt8, lsum, emb, out, 1, 0);
  } else {
    for (int c = 0; c < nc; ++c) {
      const int ch0 = c * RC;
      k_s_full<<<dim3(RC / 128, NROWS / 128), 256, 0, stream>>>(xb, E, lsum, ch0);
      k_pv8<<<dim3(NDIM / 128, RC / 128), 256, 0, stream>>>(E, Vt8, lsum, emb, out, 0, ch0);
    }
  }
}

// Round 15
// 221.799 us; speedup vs baseline: 1.0549x; 1.0335x over previous
//
#include <hip/hip_runtime.h>
#include <hip/hip_bf16.h>

#define NROWS 8192
#define NDIM  1024
#define ESCALE 8192.0f
#define EINV   (1.0f / 8192.0f)
#define SCALE1 0x7F7F7F7F   // e8m0 = 127 -> 2^0 in every byte

// exp(10*s/256 - 10) == exp2(s*C2 + C3)
#define C2 (0.0390625f * 1.4426950408889634f)
#define C3 (-10.0f * 1.4426950408889634f)

// packed tile constants (16B-inner layout: [kseg16][row(128)][16B])
#define XTILE_B  131072ull   // bytes per packed fp8 x tile: 128 rows * 1024 k
#define PTILE_B  1048576ull  // bytes per packed fp8 E/Vt tile: 128 rows * 8192 k

typedef __attribute__((ext_vector_type(8))) int intx8;
typedef __attribute__((ext_vector_type(4))) int intx4;
typedef __attribute__((ext_vector_type(4))) float floatx4;

// async global->LDS. HW writes to (wave-uniform lds_base) + lane*16.
__device__ __forceinline__ void async16(void* lds, const void* g) {
  __builtin_amdgcn_global_load_lds(
      (const __attribute__((address_space(1))) unsigned int*)g,
      (__attribute__((address_space(3))) unsigned int*)lds, 16, 0, 0);
}

__device__ __forceinline__ unsigned char f2f8(float f) {
  return (unsigned char)(__builtin_amdgcn_cvt_pk_fp8_f32(f, 0.f, 0, false) & 0xff);
}

// read a 32-byte A/B fragment (k = quad*32..+31) from a 16B-inner LDS tile
__device__ __forceinline__ intx8 frag32s(const unsigned char* base, int quad, int row,
                                         int segsz) {
  const intx4 lo = *reinterpret_cast<const intx4*>(base + (2 * quad) * segsz + row * 16);
  const intx4 hi = *reinterpret_cast<const intx4*>(base + (2 * quad + 1) * segsz + row * 16);
  return __builtin_shufflevector(lo, hi, 0, 1, 2, 3, 4, 5, 6, 7);
}

// ------- Kernel 1: row L2-normalize -> fp8(16*x), TILE-PACKED ----------
// Wave-per-row (r14 FIX): each lane handles 4 float4 (lane + 64p, p=0..3) so
// the full 1024-float row is covered (r14's bug: 1 float4/lane = 1/4 row).
// Pure shuffle butterfly reduce, no barriers, no LDS.
__global__ __launch_bounds__(256) void k_norm(const float* __restrict__ emb,
                                              unsigned char* __restrict__ xb) {
  const int t = threadIdx.x;
  const int lane = t & 63;
  const int row = blockIdx.x * 4 + (t >> 6);
  const float4* src = reinterpret_cast<const float4*>(emb + (size_t)row * NDIM);
  float4 v[4];
  float ss = 0.f;
#pragma unroll
  for (int p = 0; p < 4; ++p) {
    v[p] = src[lane + 64 * p];
    ss += v[p].x * v[p].x + v[p].y * v[p].y + v[p].z * v[p].z + v[p].w * v[p].w;
  }
#pragma unroll
  for (int m = 1; m < 64; m <<= 1) ss += __shfl_xor(ss, m);
  const float r16 = 16.0f / fmaxf(sqrtf(ss), 1e-12f);
  unsigned char* rowbase = xb + (size_t)(row >> 7) * XTILE_B + (row & 127) * 16;
#pragma unroll
  for (int p = 0; p < 4; ++p) {
    int pk = __builtin_amdgcn_cvt_pk_fp8_f32(v[p].x * r16, v[p].y * r16, 0, false);
    pk = __builtin_amdgcn_cvt_pk_fp8_f32(v[p].z * r16, v[p].w * r16, pk, true);
    const int k = (lane + 64 * p) * 4;
    *reinterpret_cast<int*>(rowbase + (k >> 4) * 2048 + (k & 15)) = pk;
  }
}

// ------- Kernel 2: transpose emb -> Vt fp8, TILE-PACKED ----------
// Pitch 73 (was 72): 72 gave a 16-way bank conflict on both phases.
__global__ __launch_bounds__(256) void k_tr8(const float* __restrict__ emb,
                                             unsigned char* __restrict__ Vt8) {
  __shared__ float T[64][73];
  const int r0 = blockIdx.x * 64;  // source rows (j of Vt)
  const int c0 = blockIdx.y * 64;  // source cols (d of Vt)
  const int t = threadIdx.x;
#pragma unroll
  for (int p = 0; p < 4; ++p) {
    const int r = (t >> 4) + 16 * p;
    const int c = (t & 15) * 4;
    const float4 v = *reinterpret_cast<const float4*>(emb + (size_t)(r0 + r) * NDIM + c0 + c);
    T[c + 0][r] = v.x; T[c + 1][r] = v.y; T[c + 2][r] = v.z; T[c + 3][r] = v.w;
  }
  __syncthreads();
#pragma unroll
  for (int p = 0; p < 2; ++p) {
    const int d = (t >> 3) + 32 * p;
    const int seg = t & 7;
    const float* src = &T[d][seg * 8];
    int w0 = __builtin_amdgcn_cvt_pk_fp8_f32(src[0], src[1], 0, false);
    w0 = __builtin_amdgcn_cvt_pk_fp8_f32(src[2], src[3], w0, true);
    int w1 = __builtin_amdgcn_cvt_pk_fp8_f32(src[4], src[5], 0, false);
    w1 = __builtin_amdgcn_cvt_pk_fp8_f32(src[6], src[7], w1, true);
    const int dg = c0 + d;          // global d
    const int jg = r0 + seg * 8;    // global j
    unsigned char* dst = Vt8 + (size_t)(dg >> 7) * PTILE_B +
                         (jg >> 4) * 2048 + (dg & 127) * 16 + (jg & 15);
    int2 o; o.x = w0; o.y = w1;
    *reinterpret_cast<int2*>(dst) = o;
  }
}

// ---- Kernel 3a: symmetric S -> E fp8 (packed), triangle grid, MX K=128 ----
// (256,2) low-register class (r9: 2 blocks/CU, +40%). af[4]-held COMPUTE,
// plain __syncthreads 2-phase (r10 verified best). exp2-folded epilogue.
__global__ __launch_bounds__(256, 2) void k_s_sym(const unsigned char* __restrict__ xb,
                                                  unsigned char* __restrict__ E,
                                                  float* __restrict__ lsum) {
  __shared__ __align__(16) unsigned char smem[65536];  // [buf0: A|B][buf1: A|B]
  const int tid = threadIdx.x;
  const int lane = tid & 63, w = tid >> 6;
  const int quad = lane >> 4, l15 = lane & 15;
  const int wi = w >> 1, wj = w & 1;

  // XCD-contiguous bijective remap: 2080 blocks = 8 XCD * 260
  const int idx = (blockIdx.x & 7) * 260 + (blockIdx.x >> 3);
  int bj = (int)((sqrtf(8.0f * idx + 1.0f) - 1.0f) * 0.5f);
  while ((bj + 1) * (bj + 2) / 2 <= idx) ++bj;
  while (bj * (bj + 1) / 2 > idx) --bj;
  const int bi = idx - bj * (bj + 1) / 2;
  const int it0 = bi * 128, jt0 = bj * 128;

  floatx4 acc[4][4];
#pragma unroll
  for (int a = 0; a < 4; ++a)
#pragma unroll
    for (int b = 0; b < 4; ++b) acc[a][b] = {0.f, 0.f, 0.f, 0.f};

  const unsigned char* gA = xb + (size_t)bi * XTILE_B + w * 4096 + lane * 16;
  const unsigned char* gB = xb + (size_t)bj * XTILE_B + w * 4096 + lane * 16;

  auto STAGE = [&](int buf) {  // 8 async16 per wave
    unsigned char* lA = smem + buf * 32768 + w * 4096;
    unsigned char* lB = lA + 16384;
#pragma unroll
    for (int q = 0; q < 4; ++q) {
      async16(lA + q * 1024, gA + q * 1024);
      async16(lB + q * 1024, gB + q * 1024);
    }
    gA += 16384; gB += 16384;
  };
  auto COMPUTE = [&](int buf) {
    const unsigned char* Ab = smem + buf * 32768;
    const unsigned char* Bb = Ab + 16384;
    intx8 af[4];
#pragma unroll
    for (int fm = 0; fm < 4; ++fm)
      af[fm] = frag32s(Ab, quad, wi * 64 + fm * 16 + l15, 2048);
    __builtin_amdgcn_s_setprio(1);
#pragma unroll
    for (int fn = 0; fn < 4; ++fn) {
      const intx8 bf = frag32s(Bb, quad, wj * 64 + fn * 16 + l15, 2048);
#pragma unroll
      for (int fm = 0; fm < 4; ++fm)
        acc[fm][fn] = __builtin_amdgcn_mfma_scale_f32_16x16x128_f8f6f4(
            af[fm], bf, acc[fm][fn], 0, 0, 0, SCALE1, 0, SCALE1);
    }
    __builtin_amdgcn_s_setprio(0);
  };

  // 8 K-tiles, 2-phase dbuf (unroll 1 keeps register pressure down)
  STAGE(0);
  __syncthreads();
#pragma unroll 1
  for (int kk = 0; kk < 3; ++kk) {
    STAGE(1); COMPUTE(0); __syncthreads();
    STAGE(0); COMPUTE(1); __syncthreads();
  }
  STAGE(1); COMPUTE(0); __syncthreads(); COMPUTE(1);

  // P = exp(10*s - 10); s_raw = 256*s -> p = exp2(s_raw*C2 + C3)
#pragma unroll
  for (int fm = 0; fm < 4; ++fm)
#pragma unroll
    for (int fn = 0; fn < 4; ++fn)
#pragma unroll
      for (int reg = 0; reg < 4; ++reg) {
        float p = exp2f(fmaf(acc[fm][fn][reg], C2, C3));
        if (bi == bj &&
            (wi * 64 + fm * 16 + quad * 4 + reg) == (wj * 64 + fn * 16 + l15))
          p = 0.f;
        acc[fm][fn][reg] = p;
      }

  // normal-orientation packed stores + row sums
  unsigned char* Ei = E + (size_t)bi * PTILE_B;
#pragma unroll
  for (int fm = 0; fm < 4; ++fm)
#pragma unroll
    for (int reg = 0; reg < 4; ++reg) {
      const int row = wi * 64 + fm * 16 + quad * 4 + reg;
      float s = 0.f;
#pragma unroll
      for (int fn = 0; fn < 4; ++fn) {
        const float p = acc[fm][fn][reg];
        s += p;
        Ei[((jt0 >> 4) + wj * 4 + fn) * 2048 + row * 16 + l15] = f2f8(p * ESCALE);
      }
#pragma unroll
      for (int m = 1; m < 16; m <<= 1) s += __shfl_xor(s, m);
      if (l15 == 0) unsafeAtomicAdd(&lsum[it0 + row], s);
    }

  if (bi != bj) {  // transposed packed store + col sums
    unsigned char* Ej = E + (size_t)bj * PTILE_B;
#pragma unroll
    for (int fn = 0; fn < 4; ++fn) {
      const int col = wj * 64 + fn * 16 + l15;  // i-local row within tile bj
      float cs = 0.f;
#pragma unroll
      for (int fm = 0; fm < 4; ++fm) {
        int pk = __builtin_amdgcn_cvt_pk_fp8_f32(acc[fm][fn][0] * ESCALE,
                                                 acc[fm][fn][1] * ESCALE, 0, false);
        pk = __builtin_amdgcn_cvt_pk_fp8_f32(acc[fm][fn][2] * ESCALE,
                                             acc[fm][fn][3] * ESCALE, pk, true);
        cs += acc[fm][fn][0] + acc[fm][fn][1] + acc[fm][fn][2] + acc[fm][fn][3];
        *reinterpret_cast<int*>(
            &Ej[((it0 >> 4) + wi * 4 + fm) * 2048 + col * 16 + quad * 4]) = pk;
      }
      cs += __shfl_xor(cs, 16);
      cs += __shfl_xor(cs, 32);
      if (quad == 0) unsafeAtomicAdd(&lsum[jt0 + col], cs);
    }
  }
}

// ---------------- Kernel 3b: full-grid fallback (chunked, packed) ----------
__global__ __launch_bounds__(256) void k_s_full(const unsigned char* __restrict__ xb,
                                                unsigned char* __restrict__ E,
                                                float* __restrict__ lsum, int ch0) {
  __shared__ __align__(16) unsigned char smem[65536];
  const int tid = threadIdx.x;
  const int lane = tid & 63, w = tid >> 6;
  const int quad = lane >> 4, l15 = lane & 15;
  const int wi = w >> 1, wj = w & 1;
  const int bi = blockIdx.x;       // chunk-local i tile
  const int bj = blockIdx.y;       // global j tile
  const int it0 = bi * 128, jt0 = bj * 128;

  floatx4 acc[4][4];
#pragma unroll
  for (int a = 0; a < 4; ++a)
#pragma unroll
    for (int b = 0; b < 4; ++b) acc[a][b] = {0.f, 0.f, 0.f, 0.f};

  const unsigned char* gA =
      xb + (size_t)((ch0 >> 7) + bi) * XTILE_B + w * 4096 + lane * 16;
  const unsigned char* gB = xb + (size_t)bj * XTILE_B + w * 4096 + lane * 16;

  auto STAGE = [&](int buf) {
    unsigned char* lA = smem + buf * 32768 + w * 4096;
    unsigned char* lB = lA + 16384;
#pragma unroll
    for (int q = 0; q < 4; ++q) {
      async16(lA + q * 1024, gA + q * 1024);
      async16(lB + q * 1024, gB + q * 1024);
    }
    gA += 16384; gB += 16384;
  };
  auto COMPUTE = [&](int buf) {
    const unsigned char* Ab = smem + buf * 32768;
    const unsigned char* Bb = Ab + 16384;
    intx8 bf[4];
#pragma unroll
    for (int fn = 0; fn < 4; ++fn)
      bf[fn] = frag32s(Bb, quad, wj * 64 + fn * 16 + l15, 2048);
    __builtin_amdgcn_s_setprio(1);
#pragma unroll
    for (int fm = 0; fm < 4; ++fm) {
      const intx8 af = frag32s(Ab, quad, wi * 64 + fm * 16 + l15, 2048);
#pragma unroll
      for (int fn = 0; fn < 4; ++fn)
        acc[fm][fn] = __builtin_amdgcn_mfma_scale_f32_16x16x128_f8f6f4(
            af, bf[fn], acc[fm][fn], 0, 0, 0, SCALE1, 0, SCALE1);
    }
    __builtin_amdgcn_s_setprio(0);
  };

  STAGE(0);
  __syncthreads();
#pragma unroll
  for (int kk = 0; kk < 6; kk += 2) {
    STAGE(1); COMPUTE(0); __syncthreads();
    STAGE(0); COMPUTE(1); __syncthreads();
  }
  STAGE(1); COMPUTE(0); __syncthreads(); COMPUTE(1);

  unsigned char* Ei = E + (size_t)bi * PTILE_B;
#pragma unroll
  for (int fm = 0; fm < 4; ++fm)
#pragma unroll
    for (int reg = 0; reg < 4; ++reg) {
      const int row = wi * 64 + fm * 16 + quad * 4 + reg;
      float s = 0.f;
#pragma unroll
      for (int fn = 0; fn < 4; ++fn) {
        const int col = jt0 + wj * 64 + fn * 16 + l15;
        float p = exp2f(fmaf(acc[fm][fn][reg], C2, C3));
        if (ch0 + it0 + row == col) p = 0.f;
        s += p;
        Ei[(col >> 4) * 2048 + row * 16 + (col & 15)] = f2f8(p * ESCALE);
      }
#pragma unroll
      for (int m = 1; m < 16; m <<= 1) s += __shfl_xor(s, m);
      if (l15 == 0) unsafeAtomicAdd(&lsum[ch0 + it0 + row], s);
    }
}

// -------- Kernel 4: out^T = Vt8 @ E^T (MX fp8 K=128, packed operands) ------
// (256,2), fn-halves, plain 2-phase syncthreads (r10 verified best).
__global__ __launch_bounds__(256, 2) void k_pv8(const unsigned char* __restrict__ E,
                                                const unsigned char* __restrict__ Vt8,
                                                const float* __restrict__ lsum,
                                                const float* __restrict__ emb,
                                                float* __restrict__ out,
                                                int swz, int ch0) {
  __shared__ __align__(16) unsigned char smem[65536];
  const int tid = threadIdx.x;
  const int lane = tid & 63, w = tid >> 6;
  const int quad = lane >> 4, l15 = lane & 15;
  const int wi = w >> 1, wj = w & 1;

  int dt, it;
  if (swz) {
    const int n = blockIdx.x;
    const int r = n & 7, q = n >> 3;
    dt = q >> 3; it = (q & 7) * 8 + r;
  } else {
    dt = blockIdx.x; it = blockIdx.y;
  }
  const int dt0 = dt * 128, it0 = it * 128;

  floatx4 acc[4][4];
#pragma unroll
  for (int a = 0; a < 4; ++a)
#pragma unroll
    for (int b = 0; b < 4; ++b) acc[a][b] = {0.f, 0.f, 0.f, 0.f};

  const unsigned char* gA = Vt8 + (size_t)dt * PTILE_B + w * 4096 + lane * 16;
  const unsigned char* gB = E + (size_t)it * PTILE_B + w * 4096 + lane * 16;

  auto STAGE = [&](int buf) {  // 8 async16 per wave
    unsigned char* lA = smem + buf * 32768 + w * 4096;
    unsigned char* lB = lA + 16384;
#pragma unroll
    for (int q = 0; q < 4; ++q) {
      async16(lA + q * 1024, gA + q * 1024);
      async16(lB + q * 1024, gB + q * 1024);
    }
    gA += 16384; gB += 16384;
  };
  auto COMPUTE = [&](int buf) {
    const unsigned char* Ab = smem + buf * 32768;
    const unsigned char* Bb = Ab + 16384;
    __builtin_amdgcn_s_setprio(1);
#pragma unroll
    for (int h = 0; h < 2; ++h) {
      const intx8 bf0 = frag32s(Bb, quad, wj * 64 + (2 * h) * 16 + l15, 2048);
      const intx8 bf1 = frag32s(Bb, quad, wj * 64 + (2 * h + 1) * 16 + l15, 2048);
#pragma unroll
      for (int fm = 0; fm < 4; ++fm) {
        const intx8 af = frag32s(Ab, quad, wi * 64 + fm * 16 + l15, 2048);
        acc[fm][2 * h] = __builtin_amdgcn_mfma_scale_f32_16x16x128_f8f6f4(
            af, bf0, acc[fm][2 * h], 0, 0, 0, SCALE1, 0, SCALE1);
        acc[fm][2 * h + 1] = __builtin_amdgcn_mfma_scale_f32_16x16x128_f8f6f4(
            af, bf1, acc[fm][2 * h + 1], 0, 0, 0, SCALE1, 0, SCALE1);
      }
    }
    __builtin_amdgcn_s_setprio(0);
  };

  // 64 K-tiles, 2-phase dbuf
  STAGE(0);
  __syncthreads();
#pragma unroll 1
  for (int kk = 0; kk < 31; ++kk) {
    STAGE(1); COMPUTE(0); __syncthreads();
    STAGE(0); COMPUTE(1); __syncthreads();
  }
  STAGE(1); COMPUTE(0); __syncthreads(); COMPUTE(1);

#pragma unroll
  for (int fn = 0; fn < 4; ++fn) {
    const int i = it0 + wj * 64 + fn * 16 + l15;
    const float rinv = 1.0f / (1.0f + lsum[ch0 + i]);
#pragma unroll
    for (int fm = 0; fm < 4; ++fm) {
      const int d = dt0 + wi * 64 + fm * 16 + quad * 4;
      const float4 e = *reinterpret_cast<const float4*>(emb + (size_t)(ch0 + i) * NDIM + d);
      float4 o;
      o.x = (e.x + acc[fm][fn][0] * EINV) * rinv;
      o.y = (e.y + acc[fm][fn][1] * EINV) * rinv;
      o.z = (e.z + acc[fm][fn][2] * EINV) * rinv;
      o.w = (e.w + acc[fm][fn][3] * EINV) * rinv;
      *reinterpret_cast<float4*>(out + (size_t)(ch0 + i) * NDIM + d) = o;
    }
  }
}

extern "C" void kernel_launch(void* const* d_in, const int* in_sizes, int n_in,
                              void* d_out, int out_size, void* d_ws, size_t ws_size,
                              hipStream_t stream) {
  const float* emb = (const float*)d_in[0];
  float* out = (float*)d_out;

  unsigned char* xb = (unsigned char*)d_ws;                            // 8 MB packed fp8
  unsigned char* Vt8 = (unsigned char*)((char*)d_ws + (8ull << 20));   // 8 MB packed fp8
  float* lsum = (float*)((char*)d_ws + (16ull << 20));                 // 32 KB
  unsigned char* E = (unsigned char*)((char*)d_ws + (17ull << 20));    // 64 MB packed fp8

  const size_t avail = ws_size > (17ull << 20) ? ws_size - (17ull << 20) : 0;
  int nc = 1;
  while (nc < 64 && ((size_t)(NROWS / nc) * NROWS) > avail) nc <<= 1;
  const int RC = NROWS / nc;

  hipMemsetAsync(lsum, 0, NROWS * sizeof(float), stream);
  k_norm<<<NROWS / 4, 256, 0, stream>>>(emb, xb);
  k_tr8<<<dim3(NROWS / 64, NDIM / 64), 256, 0, stream>>>(emb, Vt8);

  if (nc == 1) {
    const int nt = NROWS / 128;
    k_s_sym<<<nt * (nt + 1) / 2, 256, 0, stream>>>(xb, E, lsum);
    k_pv8<<<512, 256, 0, stream>>>(E, Vt8, lsum, emb, out, 1, 0);
  } else {
    for (int c = 0; c < nc; ++c) {
      const int ch0 = c * RC;
      k_s_full<<<dim3(RC / 128, NROWS / 128), 256, 0, stream>>>(xb, E, lsum, ch0);
      k_pv8<<<dim3(NDIM / 128, RC / 128), 256, 0, stream>>>(E, Vt8, lsum, emb, out, 0, ch0);
    }
  }
}

// Round 16
// 221.386 us; speedup vs baseline: 1.0569x; 1.0019x over previous
//
#include <hip/hip_runtime.h>
#include <hip/hip_bf16.h>

#define NROWS 8192
#define NDIM  1024
#define ESCALE 8192.0f
#define EINV   (1.0f / 8192.0f)
#define SCALE1 0x7F7F7F7F   // e8m0 = 127 -> 2^0 in every byte

// exp(10*s/256 - 10) == exp2(s*C2 + C3)
#define C2 (0.0390625f * 1.4426950408889634f)
#define C3 (-10.0f * 1.4426950408889634f)

// packed tile constants (16B-inner layout: [kseg16][row(128)][16B])
#define XTILE_B  131072ull   // bytes per packed fp8 x tile: 128 rows * 1024 k
#define PTILE_B  1048576ull  // bytes per packed fp8 E/Vt tile: 128 rows * 8192 k

typedef __attribute__((ext_vector_type(8))) int intx8;
typedef __attribute__((ext_vector_type(4))) int intx4;
typedef __attribute__((ext_vector_type(4))) float floatx4;

// async global->LDS. HW writes to (wave-uniform lds_base) + lane*16.
__device__ __forceinline__ void async16(void* lds, const void* g) {
  __builtin_amdgcn_global_load_lds(
      (const __attribute__((address_space(1))) unsigned int*)g,
      (__attribute__((address_space(3))) unsigned int*)lds, 16, 0, 0);
}

__device__ __forceinline__ unsigned char f2f8(float f) {
  return (unsigned char)(__builtin_amdgcn_cvt_pk_fp8_f32(f, 0.f, 0, false) & 0xff);
}

// read a 32-byte A/B fragment (k = quad*32..+31) from a 16B-inner LDS tile
__device__ __forceinline__ intx8 frag32s(const unsigned char* base, int quad, int row,
                                         int segsz) {
  const intx4 lo = *reinterpret_cast<const intx4*>(base + (2 * quad) * segsz + row * 16);
  const intx4 hi = *reinterpret_cast<const intx4*>(base + (2 * quad + 1) * segsz + row * 16);
  return __builtin_shufflevector(lo, hi, 0, 1, 2, 3, 4, 5, 6, 7);
}

// ------- Kernel 1: row L2-normalize -> fp8(16*x), TILE-PACKED ----------
// Wave-per-row: each lane handles 4 float4 (lane + 64p), full 1024-float row.
// Pure shuffle butterfly reduce, no barriers, no LDS. Also zeroes its 4 lsum
// rows (replaces the hipMemsetAsync node; k_norm precedes k_s_sym in-stream).
__global__ __launch_bounds__(256) void k_norm(const float* __restrict__ emb,
                                              unsigned char* __restrict__ xb,
                                              float* __restrict__ lsum) {
  const int t = threadIdx.x;
  const int lane = t & 63;
  const int row = blockIdx.x * 4 + (t >> 6);
  if (t < 4) lsum[blockIdx.x * 4 + t] = 0.f;
  const float4* src = reinterpret_cast<const float4*>(emb + (size_t)row * NDIM);
  float4 v[4];
  float ss = 0.f;
#pragma unroll
  for (int p = 0; p < 4; ++p) {
    v[p] = src[lane + 64 * p];
    ss += v[p].x * v[p].x + v[p].y * v[p].y + v[p].z * v[p].z + v[p].w * v[p].w;
  }
#pragma unroll
  for (int m = 1; m < 64; m <<= 1) ss += __shfl_xor(ss, m);
  const float r16 = 16.0f / fmaxf(sqrtf(ss), 1e-12f);
  unsigned char* rowbase = xb + (size_t)(row >> 7) * XTILE_B + (row & 127) * 16;
#pragma unroll
  for (int p = 0; p < 4; ++p) {
    int pk = __builtin_amdgcn_cvt_pk_fp8_f32(v[p].x * r16, v[p].y * r16, 0, false);
    pk = __builtin_amdgcn_cvt_pk_fp8_f32(v[p].z * r16, v[p].w * r16, pk, true);
    const int k = (lane + 64 * p) * 4;
    *reinterpret_cast<int*>(rowbase + (k >> 4) * 2048 + (k & 15)) = pk;
  }
}

// ------- Kernel 2: transpose emb -> Vt fp8, TILE-PACKED ----------
// Pitch 73 (was 72): 72 gave a 16-way bank conflict on both phases.
__global__ __launch_bounds__(256) void k_tr8(const float* __restrict__ emb,
                                             unsigned char* __restrict__ Vt8) {
  __shared__ float T[64][73];
  const int r0 = blockIdx.x * 64;  // source rows (j of Vt)
  const int c0 = blockIdx.y * 64;  // source cols (d of Vt)
  const int t = threadIdx.x;
#pragma unroll
  for (int p = 0; p < 4; ++p) {
    const int r = (t >> 4) + 16 * p;
    const int c = (t & 15) * 4;
    const float4 v = *reinterpret_cast<const float4*>(emb + (size_t)(r0 + r) * NDIM + c0 + c);
    T[c + 0][r] = v.x; T[c + 1][r] = v.y; T[c + 2][r] = v.z; T[c + 3][r] = v.w;
  }
  __syncthreads();
#pragma unroll
  for (int p = 0; p < 2; ++p) {
    const int d = (t >> 3) + 32 * p;
    const int seg = t & 7;
    const float* src = &T[d][seg * 8];
    int w0 = __builtin_amdgcn_cvt_pk_fp8_f32(src[0], src[1], 0, false);
    w0 = __builtin_amdgcn_cvt_pk_fp8_f32(src[2], src[3], w0, true);
    int w1 = __builtin_amdgcn_cvt_pk_fp8_f32(src[4], src[5], 0, false);
    w1 = __builtin_amdgcn_cvt_pk_fp8_f32(src[6], src[7], w1, true);
    const int dg = c0 + d;          // global d
    const int jg = r0 + seg * 8;    // global j
    unsigned char* dst = Vt8 + (size_t)(dg >> 7) * PTILE_B +
                         (jg >> 4) * 2048 + (dg & 127) * 16 + (jg & 15);
    int2 o; o.x = w0; o.y = w1;
    *reinterpret_cast<int2*>(dst) = o;
  }
}

// ---- Kernel 3a: symmetric S -> E fp8 (packed), triangle grid, MX K=128 ----
// (256,2) low-register class (r9: 2 blocks/CU, +40%). af[4]-held COMPUTE,
// plain __syncthreads 2-phase (r10 verified best). exp2-folded epilogue.
// Runs at ~916 TF MX-fp8 == the documented m97-class structural ceiling.
__global__ __launch_bounds__(256, 2) void k_s_sym(const unsigned char* __restrict__ xb,
                                                  unsigned char* __restrict__ E,
                                                  float* __restrict__ lsum) {
  __shared__ __align__(16) unsigned char smem[65536];  // [buf0: A|B][buf1: A|B]
  const int tid = threadIdx.x;
  const int lane = tid & 63, w = tid >> 6;
  const int quad = lane >> 4, l15 = lane & 15;
  const int wi = w >> 1, wj = w & 1;

  // XCD-contiguous bijective remap: 2080 blocks = 8 XCD * 260
  const int idx = (blockIdx.x & 7) * 260 + (blockIdx.x >> 3);
  int bj = (int)((sqrtf(8.0f * idx + 1.0f) - 1.0f) * 0.5f);
  while ((bj + 1) * (bj + 2) / 2 <= idx) ++bj;
  while (bj * (bj + 1) / 2 > idx) --bj;
  const int bi = idx - bj * (bj + 1) / 2;
  const int it0 = bi * 128, jt0 = bj * 128;

  floatx4 acc[4][4];
#pragma unroll
  for (int a = 0; a < 4; ++a)
#pragma unroll
    for (int b = 0; b < 4; ++b) acc[a][b] = {0.f, 0.f, 0.f, 0.f};

  const unsigned char* gA = xb + (size_t)bi * XTILE_B + w * 4096 + lane * 16;
  const unsigned char* gB = xb + (size_t)bj * XTILE_B + w * 4096 + lane * 16;

  auto STAGE = [&](int buf) {  // 8 async16 per wave
    unsigned char* lA = smem + buf * 32768 + w * 4096;
    unsigned char* lB = lA + 16384;
#pragma unroll
    for (int q = 0; q < 4; ++q) {
      async16(lA + q * 1024, gA + q * 1024);
      async16(lB + q * 1024, gB + q * 1024);
    }
    gA += 16384; gB += 16384;
  };
  auto COMPUTE = [&](int buf) {
    const unsigned char* Ab = smem + buf * 32768;
    const unsigned char* Bb = Ab + 16384;
    intx8 af[4];
#pragma unroll
    for (int fm = 0; fm < 4; ++fm)
      af[fm] = frag32s(Ab, quad, wi * 64 + fm * 16 + l15, 2048);
    __builtin_amdgcn_s_setprio(1);
#pragma unroll
    for (int fn = 0; fn < 4; ++fn) {
      const intx8 bf = frag32s(Bb, quad, wj * 64 + fn * 16 + l15, 2048);
#pragma unroll
      for (int fm = 0; fm < 4; ++fm)
        acc[fm][fn] = __builtin_amdgcn_mfma_scale_f32_16x16x128_f8f6f4(
            af[fm], bf, acc[fm][fn], 0, 0, 0, SCALE1, 0, SCALE1);
    }
    __builtin_amdgcn_s_setprio(0);
  };

  // 8 K-tiles, 2-phase dbuf (unroll 1 keeps register pressure down)
  STAGE(0);
  __syncthreads();
#pragma unroll 1
  for (int kk = 0; kk < 3; ++kk) {
    STAGE(1); COMPUTE(0); __syncthreads();
    STAGE(0); COMPUTE(1); __syncthreads();
  }
  STAGE(1); COMPUTE(0); __syncthreads(); COMPUTE(1);

  // P = exp(10*s - 10); s_raw = 256*s -> p = exp2(s_raw*C2 + C3)
#pragma unroll
  for (int fm = 0; fm < 4; ++fm)
#pragma unroll
    for (int fn = 0; fn < 4; ++fn)
#pragma unroll
      for (int reg = 0; reg < 4; ++reg) {
        float p = exp2f(fmaf(acc[fm][fn][reg], C2, C3));
        if (bi == bj &&
            (wi * 64 + fm * 16 + quad * 4 + reg) == (wj * 64 + fn * 16 + l15))
          p = 0.f;
        acc[fm][fn][reg] = p;
      }

  // normal-orientation packed stores + row sums
  unsigned char* Ei = E + (size_t)bi * PTILE_B;
#pragma unroll
  for (int fm = 0; fm < 4; ++fm)
#pragma unroll
    for (int reg = 0; reg < 4; ++reg) {
      const int row = wi * 64 + fm * 16 + quad * 4 + reg;
      float s = 0.f;
#pragma unroll
      for (int fn = 0; fn < 4; ++fn) {
        const float p = acc[fm][fn][reg];
        s += p;
        Ei[((jt0 >> 4) + wj * 4 + fn) * 2048 + row * 16 + l15] = f2f8(p * ESCALE);
      }
#pragma unroll
      for (int m = 1; m < 16; m <<= 1) s += __shfl_xor(s, m);
      if (l15 == 0) unsafeAtomicAdd(&lsum[it0 + row], s);
    }

  if (bi != bj) {  // transposed packed store + col sums (P is symmetric)
    unsigned char* Ej = E + (size_t)bj * PTILE_B;
#pragma unroll
    for (int fn = 0; fn < 4; ++fn) {
      const int col = wj * 64 + fn * 16 + l15;  // i-local row within tile bj
      float cs = 0.f;
#pragma unroll
      for (int fm = 0; fm < 4; ++fm) {
        int pk = __builtin_amdgcn_cvt_pk_fp8_f32(acc[fm][fn][0] * ESCALE,
                                                 acc[fm][fn][1] * ESCALE, 0, false);
        pk = __builtin_amdgcn_cvt_pk_fp8_f32(acc[fm][fn][2] * ESCALE,
                                             acc[fm][fn][3] * ESCALE, pk, true);
        cs += acc[fm][fn][0] + acc[fm][fn][1] + acc[fm][fn][2] + acc[fm][fn][3];
        *reinterpret_cast<int*>(
            &Ej[((it0 >> 4) + wi * 4 + fm) * 2048 + col * 16 + quad * 4]) = pk;
      }
      cs += __shfl_xor(cs, 16);
      cs += __shfl_xor(cs, 32);
      if (quad == 0) unsafeAtomicAdd(&lsum[jt0 + col], cs);
    }
  }
}

// ---------------- Kernel 3b: full-grid fallback (chunked, packed) ----------
__global__ __launch_bounds__(256) void k_s_full(const unsigned char* __restrict__ xb,
                                                unsigned char* __restrict__ E,
                                                float* __restrict__ lsum, int ch0) {
  __shared__ __align__(16) unsigned char smem[65536];
  const int tid = threadIdx.x;
  const int lane = tid & 63, w = tid >> 6;
  const int quad = lane >> 4, l15 = lane & 15;
  const int wi = w >> 1, wj = w & 1;
  const int bi = blockIdx.x;       // chunk-local i tile
  const int bj = blockIdx.y;       // global j tile
  const int it0 = bi * 128, jt0 = bj * 128;

  floatx4 acc[4][4];
#pragma unroll
  for (int a = 0; a < 4; ++a)
#pragma unroll
    for (int b = 0; b < 4; ++b) acc[a][b] = {0.f, 0.f, 0.f, 0.f};

  const unsigned char* gA =
      xb + (size_t)((ch0 >> 7) + bi) * XTILE_B + w * 4096 + lane * 16;
  const unsigned char* gB = xb + (size_t)bj * XTILE_B + w * 4096 + lane * 16;

  auto STAGE = [&](int buf) {
    unsigned char* lA = smem + buf * 32768 + w * 4096;
    unsigned char* lB = lA + 16384;
#pragma unroll
    for (int q = 0; q < 4; ++q) {
      async16(lA + q * 1024, gA + q * 1024);
      async16(lB + q * 1024, gB + q * 1024);
    }
    gA += 16384; gB += 16384;
  };
  auto COMPUTE = [&](int buf) {
    const unsigned char* Ab = smem + buf * 32768;
    const unsigned char* Bb = Ab + 16384;
    intx8 bf[4];
#pragma unroll
    for (int fn = 0; fn < 4; ++fn)
      bf[fn] = frag32s(Bb, quad, wj * 64 + fn * 16 + l15, 2048);
    __builtin_amdgcn_s_setprio(1);
#pragma unroll
    for (int fm = 0; fm < 4; ++fm) {
      const intx8 af = frag32s(Ab, quad, wi * 64 + fm * 16 + l15, 2048);
#pragma unroll
      for (int fn = 0; fn < 4; ++fn)
        acc[fm][fn] = __builtin_amdgcn_mfma_scale_f32_16x16x128_f8f6f4(
            af, bf[fn], acc[fm][fn], 0, 0, 0, SCALE1, 0, SCALE1);
    }
    __builtin_amdgcn_s_setprio(0);
  };

  STAGE(0);
  __syncthreads();
#pragma unroll
  for (int kk = 0; kk < 6; kk += 2) {
    STAGE(1); COMPUTE(0); __syncthreads();
    STAGE(0); COMPUTE(1); __syncthreads();
  }
  STAGE(1); COMPUTE(0); __syncthreads(); COMPUTE(1);

  unsigned char* Ei = E + (size_t)bi * PTILE_B;
#pragma unroll
  for (int fm = 0; fm < 4; ++fm)
#pragma unroll
    for (int reg = 0; reg < 4; ++reg) {
      const int row = wi * 64 + fm * 16 + quad * 4 + reg;
      float s = 0.f;
#pragma unroll
      for (int fn = 0; fn < 4; ++fn) {
        const int col = jt0 + wj * 64 + fn * 16 + l15;
        float p = exp2f(fmaf(acc[fm][fn][reg], C2, C3));
        if (ch0 + it0 + row == col) p = 0.f;
        s += p;
        Ei[(col >> 4) * 2048 + row * 16 + (col & 15)] = f2f8(p * ESCALE);
      }
#pragma unroll
      for (int m = 1; m < 16; m <<= 1) s += __shfl_xor(s, m);
      if (l15 == 0) unsafeAtomicAdd(&lsum[ch0 + it0 + row], s);
    }
}

// -------- Kernel 4: out^T = Vt8 @ E^T (MX fp8 K=128, packed operands) ------
// (256,2), fn-halves, plain 2-phase syncthreads (r10 verified best, ~1.9 PF).
__global__ __launch_bounds__(256, 2) void k_pv8(const unsigned char* __restrict__ E,
                                                const unsigned char* __restrict__ Vt8,
                                                const float* __restrict__ lsum,
                                                const float* __restrict__ emb,
                                                float* __restrict__ out,
                                                int swz, int ch0) {
  __shared__ __align__(16) unsigned char smem[65536];
  const int tid = threadIdx.x;
  const int lane = tid & 63, w = tid >> 6;
  const int quad = lane >> 4, l15 = lane & 15;
  const int wi = w >> 1, wj = w & 1;

  int dt, it;
  if (swz) {
    const int n = blockIdx.x;
    const int r = n & 7, q = n >> 3;
    dt = q >> 3; it = (q & 7) * 8 + r;
  } else {
    dt = blockIdx.x; it = blockIdx.y;
  }
  const int dt0 = dt * 128, it0 = it * 128;

  floatx4 acc[4][4];
#pragma unroll
  for (int a = 0; a < 4; ++a)
#pragma unroll
    for (int b = 0; b < 4; ++b) acc[a][b] = {0.f, 0.f, 0.f, 0.f};

  const unsigned char* gA = Vt8 + (size_t)dt * PTILE_B + w * 4096 + lane * 16;
  const unsigned char* gB = E + (size_t)it * PTILE_B + w * 4096 + lane * 16;

  auto STAGE = [&](int buf) {  // 8 async16 per wave
    unsigned char* lA = smem + buf * 32768 + w * 4096;
    unsigned char* lB = lA + 16384;
#pragma unroll
    for (int q = 0; q < 4; ++q) {
      async16(lA + q * 1024, gA + q * 1024);
      async16(lB + q * 1024, gB + q * 1024);
    }
    gA += 16384; gB += 16384;
  };
  auto COMPUTE = [&](int buf) {
    const unsigned char* Ab = smem + buf * 32768;
    const unsigned char* Bb = Ab + 16384;
    __builtin_amdgcn_s_setprio(1);
#pragma unroll
    for (int h = 0; h < 2; ++h) {
      const intx8 bf0 = frag32s(Bb, quad, wj * 64 + (2 * h) * 16 + l15, 2048);
      const intx8 bf1 = frag32s(Bb, quad, wj * 64 + (2 * h + 1) * 16 + l15, 2048);
#pragma unroll
      for (int fm = 0; fm < 4; ++fm) {
        const intx8 af = frag32s(Ab, quad, wi * 64 + fm * 16 + l15, 2048);
        acc[fm][2 * h] = __builtin_amdgcn_mfma_scale_f32_16x16x128_f8f6f4(
            af, bf0, acc[fm][2 * h], 0, 0, 0, SCALE1, 0, SCALE1);
        acc[fm][2 * h + 1] = __builtin_amdgcn_mfma_scale_f32_16x16x128_f8f6f4(
            af, bf1, acc[fm][2 * h + 1], 0, 0, 0, SCALE1, 0, SCALE1);
      }
    }
    __builtin_amdgcn_s_setprio(0);
  };

  // 64 K-tiles, 2-phase dbuf
  STAGE(0);
  __syncthreads();
#pragma unroll 1
  for (int kk = 0; kk < 31; ++kk) {
    STAGE(1); COMPUTE(0); __syncthreads();
    STAGE(0); COMPUTE(1); __syncthreads();
  }
  STAGE(1); COMPUTE(0); __syncthreads(); COMPUTE(1);

#pragma unroll
  for (int fn = 0; fn < 4; ++fn) {
    const int i = it0 + wj * 64 + fn * 16 + l15;
    const float rinv = 1.0f / (1.0f + lsum[ch0 + i]);
#pragma unroll
    for (int fm = 0; fm < 4; ++fm) {
      const int d = dt0 + wi * 64 + fm * 16 + quad * 4;
      const float4 e = *reinterpret_cast<const float4*>(emb + (size_t)(ch0 + i) * NDIM + d);
      float4 o;
      o.x = (e.x + acc[fm][fn][0] * EINV) * rinv;
      o.y = (e.y + acc[fm][fn][1] * EINV) * rinv;
      o.z = (e.z + acc[fm][fn][2] * EINV) * rinv;
      o.w = (e.w + acc[fm][fn][3] * EINV) * rinv;
      *reinterpret_cast<float4*>(out + (size_t)(ch0 + i) * NDIM + d) = o;
    }
  }
}

extern "C" void kernel_launch(void* const* d_in, const int* in_sizes, int n_in,
                              void* d_out, int out_size, void* d_ws, size_t ws_size,
                              hipStream_t stream) {
  const float* emb = (const float*)d_in[0];
  float* out = (float*)d_out;

  unsigned char* xb = (unsigned char*)d_ws;                            // 8 MB packed fp8
  unsigned char* Vt8 = (unsigned char*)((char*)d_ws + (8ull << 20));   // 8 MB packed fp8
  float* lsum = (float*)((char*)d_ws + (16ull << 20));                 // 32 KB
  unsigned char* E = (unsigned char*)((char*)d_ws + (17ull << 20));    // 64 MB packed fp8

  const size_t avail = ws_size > (17ull << 20) ? ws_size - (17ull << 20) : 0;
  int nc = 1;
  while (nc < 64 && ((size_t)(NROWS / nc) * NROWS) > avail) nc <<= 1;
  const int RC = NROWS / nc;

  // k_norm zeroes lsum (replaces hipMemsetAsync; precedes k_s_sym in-stream)
  k_norm<<<NROWS / 4, 256, 0, stream>>>(emb, xb, lsum);
  k_tr8<<<dim3(NROWS / 64, NDIM / 64), 256, 0, stream>>>(emb, Vt8);

  if (nc == 1) {
    const int nt = NROWS / 128;
    k_s_sym<<<nt * (nt + 1) / 2, 256, 0, stream>>>(xb, E, lsum);
    k_pv8<<<512, 256, 0, stream>>>(E, Vt8, lsum, emb, out, 1, 0);
  } else {
    for (int c = 0; c < nc; ++c) {
      const int ch0 = c * RC;
      k_s_full<<<dim3(RC / 128, NROWS / 128), 256, 0, stream>>>(xb, E, lsum, ch0);
      k_pv8<<<dim3(NDIM / 128, RC / 128), 256, 0, stream>>>(E, Vt8, lsum, emb, out, 0, ch0);
    }
  }
}

// Round 17
// 220.078 us; speedup vs baseline: 1.0632x; 1.0059x over previous
//
#include <hip/hip_runtime.h>
#include <hip/hip_bf16.h>

#define NROWS 8192
#define NDIM  1024
#define ESCALE 8192.0f
#define EINV   (1.0f / 8192.0f)
#define SCALE1 0x7F7F7F7F   // e8m0 = 127 -> 2^0 in every byte

// exp(10*s/256 - 10) == exp2(s*C2 + C3)
#define C2 (0.0390625f * 1.4426950408889634f)
#define C3 (-10.0f * 1.4426950408889634f)

// packed tile constants (16B-inner layout: [kseg16][row(128)][16B])
#define XTILE_B  131072ull   // bytes per packed fp8 x tile: 128 rows * 1024 k
#define PTILE_B  1048576ull  // bytes per packed fp8 E/Vt tile: 128 rows * 8192 k

typedef __attribute__((ext_vector_type(8))) int intx8;
typedef __attribute__((ext_vector_type(4))) int intx4;
typedef __attribute__((ext_vector_type(4))) float floatx4;

// async global->LDS. HW writes to (wave-uniform lds_base) + lane*16.
__device__ __forceinline__ void async16(void* lds, const void* g) {
  __builtin_amdgcn_global_load_lds(
      (const __attribute__((address_space(1))) unsigned int*)g,
      (__attribute__((address_space(3))) unsigned int*)lds, 16, 0, 0);
}

__device__ __forceinline__ unsigned char f2f8(float f) {
  return (unsigned char)(__builtin_amdgcn_cvt_pk_fp8_f32(f, 0.f, 0, false) & 0xff);
}

// read a 32-byte A/B fragment (k = quad*32..+31) from a 16B-inner LDS tile
__device__ __forceinline__ intx8 frag32s(const unsigned char* base, int quad, int row,
                                         int segsz) {
  const intx4 lo = *reinterpret_cast<const intx4*>(base + (2 * quad) * segsz + row * 16);
  const intx4 hi = *reinterpret_cast<const intx4*>(base + (2 * quad + 1) * segsz + row * 16);
  return __builtin_shufflevector(lo, hi, 0, 1, 2, 3, 4, 5, 6, 7);
}

// ------- Kernel P2: grid-partition-fused pre-pass (norm | tr8) ----------
// Blocks 0..2047: k_norm body (wave-per-row L2-normalize -> xb, zero lsum).
// Blocks 2048..4095: k_tr8 body (transpose -> Vt8).
// Unlike r12's fusion (which serialized phases INSIDE blocks, -11 us), this
// keeps the two independent workloads on disjoint blocks running concurrently
// and just removes one graph node + launch gap.
__global__ __launch_bounds__(256) void k_prep2(const float* __restrict__ emb,
                                               unsigned char* __restrict__ xb,
                                               unsigned char* __restrict__ Vt8,
                                               float* __restrict__ lsum) {
  __shared__ float T[64][73];   // used by tr8 half only (pitch 73: no conflicts)
  const int t = threadIdx.x;
  if (blockIdx.x < NROWS / 4) {
    // ---- norm part: 4 rows per block, one wave per row ----
    const int lane = t & 63;
    const int row = blockIdx.x * 4 + (t >> 6);
    if (t < 4) lsum[blockIdx.x * 4 + t] = 0.f;
    const float4* src = reinterpret_cast<const float4*>(emb + (size_t)row * NDIM);
    float4 v[4];
    float ss = 0.f;
#pragma unroll
    for (int p = 0; p < 4; ++p) {
      v[p] = src[lane + 64 * p];
      ss += v[p].x * v[p].x + v[p].y * v[p].y + v[p].z * v[p].z + v[p].w * v[p].w;
    }
#pragma unroll
    for (int m = 1; m < 64; m <<= 1) ss += __shfl_xor(ss, m);
    const float r16 = 16.0f / fmaxf(sqrtf(ss), 1e-12f);
    unsigned char* rowbase = xb + (size_t)(row >> 7) * XTILE_B + (row & 127) * 16;
#pragma unroll
    for (int p = 0; p < 4; ++p) {
      int pk = __builtin_amdgcn_cvt_pk_fp8_f32(v[p].x * r16, v[p].y * r16, 0, false);
      pk = __builtin_amdgcn_cvt_pk_fp8_f32(v[p].z * r16, v[p].w * r16, pk, true);
      const int k = (lane + 64 * p) * 4;
      *reinterpret_cast<int*>(rowbase + (k >> 4) * 2048 + (k & 15)) = pk;
    }
  } else {
    // ---- tr8 part: 64x64 transpose tile ----
    const int bx = blockIdx.x - NROWS / 4;
    const int r0 = (bx & 127) * 64;  // source rows (j of Vt)
    const int c0 = (bx >> 7) * 64;   // source cols (d of Vt)
#pragma unroll
    for (int p = 0; p < 4; ++p) {
      const int r = (t >> 4) + 16 * p;
      const int c = (t & 15) * 4;
      const float4 v =
          *reinterpret_cast<const float4*>(emb + (size_t)(r0 + r) * NDIM + c0 + c);
      T[c + 0][r] = v.x; T[c + 1][r] = v.y; T[c + 2][r] = v.z; T[c + 3][r] = v.w;
    }
    __syncthreads();
#pragma unroll
    for (int p = 0; p < 2; ++p) {
      const int d = (t >> 3) + 32 * p;
      const int seg = t & 7;
      const float* src = &T[d][seg * 8];
      int w0 = __builtin_amdgcn_cvt_pk_fp8_f32(src[0], src[1], 0, false);
      w0 = __builtin_amdgcn_cvt_pk_fp8_f32(src[2], src[3], w0, true);
      int w1 = __builtin_amdgcn_cvt_pk_fp8_f32(src[4], src[5], 0, false);
      w1 = __builtin_amdgcn_cvt_pk_fp8_f32(src[6], src[7], w1, true);
      const int dg = c0 + d;          // global d
      const int jg = r0 + seg * 8;    // global j
      unsigned char* dst = Vt8 + (size_t)(dg >> 7) * PTILE_B +
                           (jg >> 4) * 2048 + (dg & 127) * 16 + (jg & 15);
      int2 o; o.x = w0; o.y = w1;
      *reinterpret_cast<int2*>(dst) = o;
    }
  }
}

// ---- Kernel 3a: symmetric S -> E fp8 (packed), triangle grid, MX K=128 ----
// (256,2) low-register class (r9: 2 blocks/CU, +40%). af[4]-held COMPUTE,
// plain __syncthreads 2-phase (r10 verified best). exp2-folded epilogue.
// Runs at ~916 TF MX-fp8 == the documented m97-class structural ceiling.
__global__ __launch_bounds__(256, 2) void k_s_sym(const unsigned char* __restrict__ xb,
                                                  unsigned char* __restrict__ E,
                                                  float* __restrict__ lsum) {
  __shared__ __align__(16) unsigned char smem[65536];  // [buf0: A|B][buf1: A|B]
  const int tid = threadIdx.x;
  const int lane = tid & 63, w = tid >> 6;
  const int quad = lane >> 4, l15 = lane & 15;
  const int wi = w >> 1, wj = w & 1;

  // XCD-contiguous bijective remap: 2080 blocks = 8 XCD * 260
  const int idx = (blockIdx.x & 7) * 260 + (blockIdx.x >> 3);
  int bj = (int)((sqrtf(8.0f * idx + 1.0f) - 1.0f) * 0.5f);
  while ((bj + 1) * (bj + 2) / 2 <= idx) ++bj;
  while (bj * (bj + 1) / 2 > idx) --bj;
  const int bi = idx - bj * (bj + 1) / 2;
  const int it0 = bi * 128, jt0 = bj * 128;

  floatx4 acc[4][4];
#pragma unroll
  for (int a = 0; a < 4; ++a)
#pragma unroll
    for (int b = 0; b < 4; ++b) acc[a][b] = {0.f, 0.f, 0.f, 0.f};

  const unsigned char* gA = xb + (size_t)bi * XTILE_B + w * 4096 + lane * 16;
  const unsigned char* gB = xb + (size_t)bj * XTILE_B + w * 4096 + lane * 16;

  auto STAGE = [&](int buf) {  // 8 async16 per wave
    unsigned char* lA = smem + buf * 32768 + w * 4096;
    unsigned char* lB = lA + 16384;
#pragma unroll
    for (int q = 0; q < 4; ++q) {
      async16(lA + q * 1024, gA + q * 1024);
      async16(lB + q * 1024, gB + q * 1024);
    }
    gA += 16384; gB += 16384;
  };
  auto COMPUTE = [&](int buf) {
    const unsigned char* Ab = smem + buf * 32768;
    const unsigned char* Bb = Ab + 16384;
    intx8 af[4];
#pragma unroll
    for (int fm = 0; fm < 4; ++fm)
      af[fm] = frag32s(Ab, quad, wi * 64 + fm * 16 + l15, 2048);
    __builtin_amdgcn_s_setprio(1);
#pragma unroll
    for (int fn = 0; fn < 4; ++fn) {
      const intx8 bf = frag32s(Bb, quad, wj * 64 + fn * 16 + l15, 2048);
#pragma unroll
      for (int fm = 0; fm < 4; ++fm)
        acc[fm][fn] = __builtin_amdgcn_mfma_scale_f32_16x16x128_f8f6f4(
            af[fm], bf, acc[fm][fn], 0, 0, 0, SCALE1, 0, SCALE1);
    }
    __builtin_amdgcn_s_setprio(0);
  };

  // 8 K-tiles, 2-phase dbuf (unroll 1 keeps register pressure down)
  STAGE(0);
  __syncthreads();
#pragma unroll 1
  for (int kk = 0; kk < 3; ++kk) {
    STAGE(1); COMPUTE(0); __syncthreads();
    STAGE(0); COMPUTE(1); __syncthreads();
  }
  STAGE(1); COMPUTE(0); __syncthreads(); COMPUTE(1);

  // P = exp(10*s - 10); s_raw = 256*s -> p = exp2(s_raw*C2 + C3)
#pragma unroll
  for (int fm = 0; fm < 4; ++fm)
#pragma unroll
    for (int fn = 0; fn < 4; ++fn)
#pragma unroll
      for (int reg = 0; reg < 4; ++reg) {
        float p = exp2f(fmaf(acc[fm][fn][reg], C2, C3));
        if (bi == bj &&
            (wi * 64 + fm * 16 + quad * 4 + reg) == (wj * 64 + fn * 16 + l15))
          p = 0.f;
        acc[fm][fn][reg] = p;
      }

  // normal-orientation packed stores + row sums
  unsigned char* Ei = E + (size_t)bi * PTILE_B;
#pragma unroll
  for (int fm = 0; fm < 4; ++fm)
#pragma unroll
    for (int reg = 0; reg < 4; ++reg) {
      const int row = wi * 64 + fm * 16 + quad * 4 + reg;
      float s = 0.f;
#pragma unroll
      for (int fn = 0; fn < 4; ++fn) {
        const float p = acc[fm][fn][reg];
        s += p;
        Ei[((jt0 >> 4) + wj * 4 + fn) * 2048 + row * 16 + l15] = f2f8(p * ESCALE);
      }
#pragma unroll
      for (int m = 1; m < 16; m <<= 1) s += __shfl_xor(s, m);
      if (l15 == 0) unsafeAtomicAdd(&lsum[it0 + row], s);
    }

  if (bi != bj) {  // transposed packed store + col sums (P is symmetric)
    unsigned char* Ej = E + (size_t)bj * PTILE_B;
#pragma unroll
    for (int fn = 0; fn < 4; ++fn) {
      const int col = wj * 64 + fn * 16 + l15;  // i-local row within tile bj
      float cs = 0.f;
#pragma unroll
      for (int fm = 0; fm < 4; ++fm) {
        int pk = __builtin_amdgcn_cvt_pk_fp8_f32(acc[fm][fn][0] * ESCALE,
                                                 acc[fm][fn][1] * ESCALE, 0, false);
        pk = __builtin_amdgcn_cvt_pk_fp8_f32(acc[fm][fn][2] * ESCALE,
                                             acc[fm][fn][3] * ESCALE, pk, true);
        cs += acc[fm][fn][0] + acc[fm][fn][1] + acc[fm][fn][2] + acc[fm][fn][3];
        *reinterpret_cast<int*>(
            &Ej[((it0 >> 4) + wi * 4 + fm) * 2048 + col * 16 + quad * 4]) = pk;
      }
      cs += __shfl_xor(cs, 16);
      cs += __shfl_xor(cs, 32);
      if (quad == 0) unsafeAtomicAdd(&lsum[jt0 + col], cs);
    }
  }
}

// ---------------- Kernel 3b: full-grid fallback (chunked, packed) ----------
__global__ __launch_bounds__(256) void k_s_full(const unsigned char* __restrict__ xb,
                                                unsigned char* __restrict__ E,
                                                float* __restrict__ lsum, int ch0) {
  __shared__ __align__(16) unsigned char smem[65536];
  const int tid = threadIdx.x;
  const int lane = tid & 63, w = tid >> 6;
  const int quad = lane >> 4, l15 = lane & 15;
  const int wi = w >> 1, wj = w & 1;
  const int bi = blockIdx.x;       // chunk-local i tile
  const int bj = blockIdx.y;       // global j tile
  const int it0 = bi * 128, jt0 = bj * 128;

  floatx4 acc[4][4];
#pragma unroll
  for (int a = 0; a < 4; ++a)
#pragma unroll
    for (int b = 0; b < 4; ++b) acc[a][b] = {0.f, 0.f, 0.f, 0.f};

  const unsigned char* gA =
      xb + (size_t)((ch0 >> 7) + bi) * XTILE_B + w * 4096 + lane * 16;
  const unsigned char* gB = xb + (size_t)bj * XTILE_B + w * 4096 + lane * 16;

  auto STAGE = [&](int buf) {
    unsigned char* lA = smem + buf * 32768 + w * 4096;
    unsigned char* lB = lA + 16384;
#pragma unroll
    for (int q = 0; q < 4; ++q) {
      async16(lA + q * 1024, gA + q * 1024);
      async16(lB + q * 1024, gB + q * 1024);
    }
    gA += 16384; gB += 16384;
  };
  auto COMPUTE = [&](int buf) {
    const unsigned char* Ab = smem + buf * 32768;
    const unsigned char* Bb = Ab + 16384;
    intx8 bf[4];
#pragma unroll
    for (int fn = 0; fn < 4; ++fn)
      bf[fn] = frag32s(Bb, quad, wj * 64 + fn * 16 + l15, 2048);
    __builtin_amdgcn_s_setprio(1);
#pragma unroll
    for (int fm = 0; fm < 4; ++fm) {
      const intx8 af = frag32s(Ab, quad, wi * 64 + fm * 16 + l15, 2048);
#pragma unroll
      for (int fn = 0; fn < 4; ++fn)
        acc[fm][fn] = __builtin_amdgcn_mfma_scale_f32_16x16x128_f8f6f4(
            af, bf[fn], acc[fm][fn], 0, 0, 0, SCALE1, 0, SCALE1);
    }
    __builtin_amdgcn_s_setprio(0);
  };

  STAGE(0);
  __syncthreads();
#pragma unroll
  for (int kk = 0; kk < 6; kk += 2) {
    STAGE(1); COMPUTE(0); __syncthreads();
    STAGE(0); COMPUTE(1); __syncthreads();
  }
  STAGE(1); COMPUTE(0); __syncthreads(); COMPUTE(1);

  unsigned char* Ei = E + (size_t)bi * PTILE_B;
#pragma unroll
  for (int fm = 0; fm < 4; ++fm)
#pragma unroll
    for (int reg = 0; reg < 4; ++reg) {
      const int row = wi * 64 + fm * 16 + quad * 4 + reg;
      float s = 0.f;
#pragma unroll
      for (int fn = 0; fn < 4; ++fn) {
        const int col = jt0 + wj * 64 + fn * 16 + l15;
        float p = exp2f(fmaf(acc[fm][fn][reg], C2, C3));
        if (ch0 + it0 + row == col) p = 0.f;
        s += p;
        Ei[(col >> 4) * 2048 + row * 16 + (col & 15)] = f2f8(p * ESCALE);
      }
#pragma unroll
      for (int m = 1; m < 16; m <<= 1) s += __shfl_xor(s, m);
      if (l15 == 0) unsafeAtomicAdd(&lsum[ch0 + it0 + row], s);
    }
}

// -------- Kernel 4: out^T = Vt8 @ E^T (MX fp8 K=128, packed operands) ------
// (256,2), fn-halves, plain 2-phase syncthreads (r10 verified best, ~1.9 PF).
__global__ __launch_bounds__(256, 2) void k_pv8(const unsigned char* __restrict__ E,
                                                const unsigned char* __restrict__ Vt8,
                                                const float* __restrict__ lsum,
                                                const float* __restrict__ emb,
                                                float* __restrict__ out,
                                                int swz, int ch0) {
  __shared__ __align__(16) unsigned char smem[65536];
  const int tid = threadIdx.x;
  const int lane = tid & 63, w = tid >> 6;
  const int quad = lane >> 4, l15 = lane & 15;
  const int wi = w >> 1, wj = w & 1;

  int dt, it;
  if (swz) {
    const int n = blockIdx.x;
    const int r = n & 7, q = n >> 3;
    dt = q >> 3; it = (q & 7) * 8 + r;
  } else {
    dt = blockIdx.x; it = blockIdx.y;
  }
  const int dt0 = dt * 128, it0 = it * 128;

  floatx4 acc[4][4];
#pragma unroll
  for (int a = 0; a < 4; ++a)
#pragma unroll
    for (int b = 0; b < 4; ++b) acc[a][b] = {0.f, 0.f, 0.f, 0.f};

  const unsigned char* gA = Vt8 + (size_t)dt * PTILE_B + w * 4096 + lane * 16;
  const unsigned char* gB = E + (size_t)it * PTILE_B + w * 4096 + lane * 16;

  auto STAGE = [&](int buf) {  // 8 async16 per wave
    unsigned char* lA = smem + buf * 32768 + w * 4096;
    unsigned char* lB = lA + 16384;
#pragma unroll
    for (int q = 0; q < 4; ++q) {
      async16(lA + q * 1024, gA + q * 1024);
      async16(lB + q * 1024, gB + q * 1024);
    }
    gA += 16384; gB += 16384;
  };
  auto COMPUTE = [&](int buf) {
    const unsigned char* Ab = smem + buf * 32768;
    const unsigned char* Bb = Ab + 16384;
    __builtin_amdgcn_s_setprio(1);
#pragma unroll
    for (int h = 0; h < 2; ++h) {
      const intx8 bf0 = frag32s(Bb, quad, wj * 64 + (2 * h) * 16 + l15, 2048);
      const intx8 bf1 = frag32s(Bb, quad, wj * 64 + (2 * h + 1) * 16 + l15, 2048);
#pragma unroll
      for (int fm = 0; fm < 4; ++fm) {
        const intx8 af = frag32s(Ab, quad, wi * 64 + fm * 16 + l15, 2048);
        acc[fm][2 * h] = __builtin_amdgcn_mfma_scale_f32_16x16x128_f8f6f4(
            af, bf0, acc[fm][2 * h], 0, 0, 0, SCALE1, 0, SCALE1);
        acc[fm][2 * h + 1] = __builtin_amdgcn_mfma_scale_f32_16x16x128_f8f6f4(
            af, bf1, acc[fm][2 * h + 1], 0, 0, 0, SCALE1, 0, SCALE1);
      }
    }
    __builtin_amdgcn_s_setprio(0);
  };

  // 64 K-tiles, 2-phase dbuf
  STAGE(0);
  __syncthreads();
#pragma unroll 1
  for (int kk = 0; kk < 31; ++kk) {
    STAGE(1); COMPUTE(0); __syncthreads();
    STAGE(0); COMPUTE(1); __syncthreads();
  }
  STAGE(1); COMPUTE(0); __syncthreads(); COMPUTE(1);

#pragma unroll
  for (int fn = 0; fn < 4; ++fn) {
    const int i = it0 + wj * 64 + fn * 16 + l15;
    const float rinv = 1.0f / (1.0f + lsum[ch0 + i]);
#pragma unroll
    for (int fm = 0; fm < 4; ++fm) {
      const int d = dt0 + wi * 64 + fm * 16 + quad * 4;
      const float4 e = *reinterpret_cast<const float4*>(emb + (size_t)(ch0 + i) * NDIM + d);
      float4 o;
      o.x = (e.x + acc[fm][fn][0] * EINV) * rinv;
      o.y = (e.y + acc[fm][fn][1] * EINV) * rinv;
      o.z = (e.z + acc[fm][fn][2] * EINV) * rinv;
      o.w = (e.w + acc[fm][fn][3] * EINV) * rinv;
      *reinterpret_cast<float4*>(out + (size_t)(ch0 + i) * NDIM + d) = o;
    }
  }
}

extern "C" void kernel_launch(void* const* d_in, const int* in_sizes, int n_in,
                              void* d_out, int out_size, void* d_ws, size_t ws_size,
                              hipStream_t stream) {
  const float* emb = (const float*)d_in[0];
  float* out = (float*)d_out;

  unsigned char* xb = (unsigned char*)d_ws;                            // 8 MB packed fp8
  unsigned char* Vt8 = (unsigned char*)((char*)d_ws + (8ull << 20));   // 8 MB packed fp8
  float* lsum = (float*)((char*)d_ws + (16ull << 20));                 // 32 KB
  unsigned char* E = (unsigned char*)((char*)d_ws + (17ull << 20));    // 64 MB packed fp8

  const size_t avail = ws_size > (17ull << 20) ? ws_size - (17ull << 20) : 0;
  int nc = 1;
  while (nc < 64 && ((size_t)(NROWS / nc) * NROWS) > avail) nc <<= 1;
  const int RC = NROWS / nc;

  // fused pre-pass: blocks 0..2047 norm+lsum-zero, 2048..4095 transpose
  k_prep2<<<NROWS / 4 + (NROWS / 64) * (NDIM / 64), 256, 0, stream>>>(emb, xb, Vt8, lsum);

  if (nc == 1) {
    const int nt = NROWS / 128;
    k_s_sym<<<nt * (nt + 1) / 2, 256, 0, stream>>>(xb, E, lsum);
    k_pv8<<<512, 256, 0, stream>>>(E, Vt8, lsum, emb, out, 1, 0);
  } else {
    for (int c = 0; c < nc; ++c) {
      const int ch0 = c * RC;
      k_s_full<<<dim3(RC / 128, NROWS / 128), 256, 0, stream>>>(xb, E, lsum, ch0);
      k_pv8<<<dim3(NDIM / 128, RC / 128), 256, 0, stream>>>(E, Vt8, lsum, emb, out, 0, ch0);
    }
  }
}